// Round 6
// baseline (1537.747 us; speedup 1.0000x reference)
//
#include <hip/hip_runtime.h>
#include <hip/hip_bf16.h>
#include <math.h>

#define B_    4
#define C_    128
#define H_    128
#define W_    128
#define HW_   (H_*W_)
#define NCLS_ 80
#define KTOP  100
#define CAPB  2048

typedef __attribute__((ext_vector_type(8)))  short bf16x8;
typedef __attribute__((ext_vector_type(16))) float f32x16;

// W image (register-load layout): per conv 36 stages of 16KB:
//   stage s = chunk*9+tap : [g 4][ks 2][part 2][32 couts x 32B]
//   lane l reads 16B at ((l&31)*32 + (l>>5)*16) -> row l31, k-half kh
#define WSTG_B     16384
#define WIMG_B     589824           // 36*16384
#define NIMG       7
// X'' image: [b*4+chunk] x [row 0..129] x [col 0..129] x 144B
#define XROWB      144
#define XCOLS      130
#define XPITCH     (XCOLS * XROWB)              // 18720
#define XSZ        ((size_t)16 * 130 * XPITCH)  // 38,937,600 per buffer
// Tile 16x4 px: halo 18x6 = 108 positions
#define XLDS_B     15552                        // 108 pos * 144B
#define LDS_TOT    (2 * XLDS_B)                 // 31104 (double-buffered X) -> 4 blocks/CU
#define ZERO_N     20512                        // hists + scalars

__device__ __forceinline__ unsigned bf16_rne(float x) {
    unsigned u = __float_as_uint(x);
    return (u + 0x7FFFu + ((u >> 16) & 1u)) >> 16;
}
__device__ __forceinline__ void split2(float v0, float v1, unsigned& hiP, unsigned& loP) {
    unsigned h0 = bf16_rne(v0), h1 = bf16_rne(v1);
    float r0 = v0 - __uint_as_float(h0 << 16);
    float r1 = v1 - __uint_as_float(h1 << 16);
    unsigned l0 = bf16_rne(r0), l1 = bf16_rne(r1);
    hiP = h0 | (h1 << 16);
    loP = l0 | (l1 << 16);
}

#define MFMA32(a, bvec, c) __builtin_amdgcn_mfma_f32_32x32x16_bf16(a, bvec, c, 0, 0, 0)

// ---------------------------------------------------------------------------
// init: X'' borders (both buffers) + small scratch + loss slot
// ---------------------------------------------------------------------------
__global__ __launch_bounds__(256) void init_k(char* __restrict__ xa, char* __restrict__ xb,
                                              unsigned* __restrict__ sm, float* __restrict__ loss)
{
    const int i = blockIdx.x * 256 + threadIdx.x;
    if (i < 16512) {
        char* buf = (i < 8256) ? xa : xb;
        const int j = (i < 8256) ? i : i - 8256;
        int R, col;
        if (j < 4160) {
            const int g = j / 260, rr = j % 260;
            R = g * 130 + ((rr < 130) ? 0 : 129);
            col = rr % 130;
        } else {
            const int q = j - 4160;
            const int g = q / 256, m = q % 256;
            R = g * 130 + 1 + (m >> 1);
            col = (m & 1) ? 129 : 0;
        }
        char* p = buf + ((size_t)R * XCOLS + col) * XROWB;
        #pragma unroll
        for (int k = 0; k < 9; k++) *(uint4*)(p + k * 16) = make_uint4(0, 0, 0, 0);
    } else {
        const int k = i - 16512;
        if (k < ZERO_N) sm[k] = 0u;
        if (k == ZERO_N) *loss = 0.f;
    }
}

// ---------------------------------------------------------------------------
// Weight transform into the register-load layout.
// Images: 0=clsL1 1=bboxL1 2=offL1 3=clsL2 4=bboxL2 5=offL2 6=score
// ---------------------------------------------------------------------------
struct WtArgs { const float* src[NIMG]; int cout[NIMG]; };

__global__ __launch_bounds__(256) void wtx_k(WtArgs a, unsigned short* wt)
{
    const int img = blockIdx.z;
    const int idx = blockIdx.x * 256 + threadIdx.x;   // < 18432
    const int h  = idx & 1;
    const int ks = (idx >> 1) & 1;
    const int r  = (idx >> 2) & 31;
    const int g  = (idx >> 7) & 3;
    const int st = idx >> 9;
    if (st >= 36) return;
    const int tap = st % 9, chunk = st / 9;
    const float* w = a.src[img];
    const int Cout = a.cout[img];
    const int cout = g * 32 + r;
    const int cin0 = chunk * 32 + ks * 16 + h * 8;
    float v[8];
    #pragma unroll
    for (int j = 0; j < 8; j++)
        v[j] = (cout < Cout) ? w[((size_t)cout * 128 + cin0 + j) * 9 + tap] : 0.f;
    unsigned hiW[4], loW[4];
    #pragma unroll
    for (int j = 0; j < 4; j++) split2(v[2 * j], v[2 * j + 1], hiW[j], loW[j]);
    char* dst = (char*)wt + (size_t)img * WIMG_B + (size_t)st * WSTG_B
              + g * 4096 + ks * 2048 + r * 32 + h * 16;
    *(uint4*)dst          = make_uint4(hiW[0], hiW[1], hiW[2], hiW[3]);
    *(uint4*)(dst + 1024) = make_uint4(loW[0], loW[1], loW[2], loW[3]);
}

// ---------------------------------------------------------------------------
// Shared epilogue: wave = 64 couts (wm) x 32 pixels (wn over 64-px tile)
// ---------------------------------------------------------------------------
template<int RELU, int XOUT>
__device__ __forceinline__ void conv_epilogue(
    f32x16 (&acc)[2], const bool* act,
    const float* bias, float* outf, char* outx, int Cout,
    int b, int x0, int y0, int wm, int wn, int kh, int l31)
{
    const int p = wn * 32 + l31;    // 0..63 within 16x4 tile
    #pragma unroll
    for (int f = 0; f < 2; f++) {
        if (!act[f]) continue;
        if (XOUT == 0) {
            #pragma unroll
            for (int r = 0; r < 16; r++) {
                const int co = wm * 64 + f * 32 + 4 * kh + (r & 3) + 8 * (r >> 2);
                if (co < Cout) {
                    float v = acc[f][r] + bias[co];
                    if (RELU) v = fmaxf(v, 0.f);
                    outf[((size_t)b * Cout + co) * HW_ + (size_t)(y0 + (p >> 4)) * 128 + (x0 + (p & 15))] = v;
                }
            }
        } else {
            const int chunkO = wm * 2 + f;
            #pragma unroll
            for (int r2 = 0; r2 < 8; r2++) {
                const int r = 2 * r2;
                const int cij = 4 * kh + (r & 3) + 8 * (r >> 2);
                const int co0 = wm * 64 + f * 32 + cij;
                float v0 = acc[f][r] + bias[co0];
                float v1 = acc[f][r + 1] + bias[co0 + 1];
                if (RELU) { v0 = fmaxf(v0, 0.f); v1 = fmaxf(v1, 0.f); }
                unsigned hiP, loP; split2(v0, v1, hiP, loP);
                char* rowp = outx + ((size_t)((b * 4 + chunkO) * 130 + (y0 + (p >> 4) + 1)) * XCOLS
                                    + (x0 + (p & 15) + 1)) * XROWB;
                *(unsigned*)(rowp + 2 * cij)      = hiP;
                *(unsigned*)(rowp + 64 + 2 * cij) = loP;
            }
        }
    }
}

// W prefetch: 2-slot rotation; slot = 2 f-groups x 2 ks x hi/lo = 8 bf16x8
// (32 VGPR). [f*2+ks] = hi, [4+f*2+ks] = lo. All indices literals.
#define WLOAD_(SLOT, SIDX) do {                                               \
    const char* wp_ = wb + (size_t)(SIDX) * WSTG_B;                           \
    _Pragma("unroll")                                                         \
    for (int f_ = 0; f_ < 2; f_++) if (act[f_]) {                             \
        _Pragma("unroll")                                                     \
        for (int k_ = 0; k_ < 2; k_++) {                                      \
            wf[SLOT][f_ * 2 + k_]     = *(const bf16x8*)(wp_ + f_ * 4096 + k_ * 2048);        \
            wf[SLOT][4 + f_ * 2 + k_] = *(const bf16x8*)(wp_ + f_ * 4096 + k_ * 2048 + 1024); \
        }                                                                     \
    }                                                                         \
} while (0)

// Per tap: 4 ds_read_b128 feed 12 MFMAs.
#define MFMA_TAP_(CUR, DOFF) do {                                             \
    _Pragma("unroll")                                                         \
    for (int ks = 0; ks < 2; ks++) {                                          \
        bf16x8 bh = *(const bf16x8*)(lds + baddr + (DOFF) + ks * 32);         \
        bf16x8 bl = *(const bf16x8*)(lds + baddr + (DOFF) + ks * 32 + 64);    \
        _Pragma("unroll")                                                     \
        for (int f = 0; f < 2; f++) if (act[f])                               \
            acc[f] = MFMA32(wf[CUR][f * 2 + ks], bh, acc[f]);                 \
        _Pragma("unroll")                                                     \
        for (int f = 0; f < 2; f++) if (act[f])                               \
            acc[f] = MFMA32(wf[CUR][f * 2 + ks], bl, acc[f]);                 \
        _Pragma("unroll")                                                     \
        for (int f = 0; f < 2; f++) if (act[f])                               \
            acc[f] = MFMA32(wf[CUR][4 + f * 2 + ks], bh, acc[f]);             \
    }                                                                         \
} while (0)

// ---------------------------------------------------------------------------
// MFMA conv, fp32 input. Tile 16x4, grid 1024 (4 blocks/CU). 4 waves:
// wave = 64 couts x 32 px. W direct global->reg, 2-slot prefetch;
// X double-buffered in LDS.
// ---------------------------------------------------------------------------
template<int RELU, int XOUT>
__global__ __launch_bounds__(256, 2) void conv_f_k(
    const float* __restrict__ in, const unsigned short* __restrict__ wt,
    const float* __restrict__ bias, float* __restrict__ outf,
    char* __restrict__ outx, int Cout)
{
    __shared__ __align__(16) char lds[LDS_TOT];

    const int t    = threadIdx.x;
    const int lane = t & 63;
    const int wv   = t >> 6;        // 0..3
    const int wm   = wv >> 1;       // 0..1 : 64-cout group
    const int wn   = wv & 1;        // 0..1 : 32-px group
    const int l31  = lane & 31;
    const int kh   = lane >> 5;

    const int bi = blockIdx.x;
    const int x0 = (bi & 7) << 4;
    const int y0 = ((bi >> 3) & 31) << 2;
    const int b  = bi >> 8;

    const int p0 = wn * 32 + l31;
    const int baddr = ((p0 >> 4) * 18 + (p0 & 15)) * 144 + kh * 16;

    bool act[2];
    #pragma unroll
    for (int f = 0; f < 2; f++) act[f] = (wm * 64 + f * 32) < Cout;

    const int wlane = (l31 << 5) | (kh << 4);
    const char* wb = (const char*)wt + wm * 8192 + wlane;

    f32x16 acc[2];
    #pragma unroll
    for (int f = 0; f < 2; f++)
        #pragma unroll
        for (int r = 0; r < 16; r++) acc[f][r] = 0.f;

    const float* inb = in + (size_t)b * 128 * HW_;

    bf16x8 wf[2][8];
    WLOAD_(0, 0);

    float xa[7], xb[7];
    #define LOADX(ch) do {                                                    \
        _Pragma("unroll")                                                     \
        for (int it = 0; it < 7; it++) {                                      \
            const int idx = t + it * 256;                                     \
            const int pl = idx & 15, cp = (idx >> 4) & 15, ph = idx >> 8;     \
            const int pos = ph * 16 + pl;                                     \
            float v0 = 0.f, v1 = 0.f;                                         \
            if (pos < 108) {                                                  \
                const int hy = pos / 18, hx = pos - hy * 18;                  \
                const int gy = y0 - 1 + hy, gx = x0 - 1 + hx;                 \
                if ((unsigned)gy < 128u && (unsigned)gx < 128u) {             \
                    const float* pp = inb + (size_t)((ch) * 32 + 2 * cp) * HW_ \
                                          + gy * 128 + gx;                    \
                    v0 = pp[0]; v1 = pp[HW_];                                 \
                }                                                             \
            }                                                                 \
            xa[it] = v0; xb[it] = v1;                                         \
        }                                                                     \
    } while (0)

    #define STOREX(bufsel) do {                                               \
        _Pragma("unroll")                                                     \
        for (int it = 0; it < 7; it++) {                                      \
            const int idx = t + it * 256;                                     \
            const int pl = idx & 15, cp = (idx >> 4) & 15, ph = idx >> 8;     \
            const int pos = ph * 16 + pl;                                     \
            if (pos < 108) {                                                  \
                unsigned hiP, loP; split2(xa[it], xb[it], hiP, loP);          \
                *(unsigned*)(lds + (bufsel) * XLDS_B + pos * 144 + 4 * cp)      = hiP; \
                *(unsigned*)(lds + (bufsel) * XLDS_B + pos * 144 + 64 + 4 * cp) = loP; \
            }                                                                 \
        }                                                                     \
    } while (0)

    // prologue: stage chunk 0 into buffer 0
    LOADX(0);
    STOREX(0);
    __syncthreads();

    #define TAPF(CH, TAP, CUR, NXT) do {                                      \
        if ((CH) * 9 + (TAP) + 1 < 36) WLOAD_(NXT, (CH) * 9 + (TAP) + 1);     \
        MFMA_TAP_(CUR, (((TAP) / 3) * 18 + ((TAP) % 3)) * 144 + ((CH) & 1) * XLDS_B); \
    } while (0)

    #define CHUNKF(CH, SA, SB) do {                                           \
        TAPF(CH, 0, SA, SB); TAPF(CH, 1, SB, SA); TAPF(CH, 2, SA, SB);        \
        TAPF(CH, 3, SB, SA); TAPF(CH, 4, SA, SB); TAPF(CH, 5, SB, SA);        \
        if ((CH) < 3) LOADX((CH) + 1);                                        \
        TAPF(CH, 6, SA, SB); TAPF(CH, 7, SB, SA); TAPF(CH, 8, SA, SB);        \
        if ((CH) < 3) { STOREX(((CH) + 1) & 1); __syncthreads(); }            \
    } while (0)

    CHUNKF(0, 0, 1);
    CHUNKF(1, 1, 0);
    CHUNKF(2, 0, 1);
    CHUNKF(3, 1, 0);

    #undef LOADX
    #undef STOREX
    #undef TAPF
    #undef CHUNKF
    conv_epilogue<RELU, XOUT>(acc, act, bias, outf, outx, Cout, b, x0, y0, wm, wn, kh, l31);
}

// ---------------------------------------------------------------------------
// MFMA conv, X'' input. Tile 16x4, grid 1024. W direct global->reg, 2-slot
// prefetch; X double-buffered in LDS via global_load_lds (+ reg tail).
// ---------------------------------------------------------------------------
template<int RELU, int XOUT>
__global__ __launch_bounds__(256, 2) void conv_x_k(
    const char* __restrict__ xin, const unsigned short* __restrict__ wt,
    const float* __restrict__ bias, float* __restrict__ outf,
    char* __restrict__ outx, int Cout)
{
    __shared__ __align__(16) char lds[LDS_TOT];

    const int t    = threadIdx.x;
    const int lane = t & 63;
    const int wv   = t >> 6;
    const int wm   = wv >> 1;
    const int wn   = wv & 1;
    const int l31  = lane & 31;
    const int kh   = lane >> 5;

    const int bi = blockIdx.x;
    const int x0 = (bi & 7) << 4;
    const int y0 = ((bi >> 3) & 31) << 2;
    const int b  = bi >> 8;

    const int p0 = wn * 32 + l31;
    const int baddr = (p0 >> 4) * 2592 + (p0 & 15) * 144 + kh * 16;

    bool act[2];
    #pragma unroll
    for (int f = 0; f < 2; f++) act[f] = (wm * 64 + f * 32) < Cout;

    const int wlane = (l31 << 5) | (kh << 4);
    const char* wb = (const char*)wt + wm * 8192 + wlane;

    f32x16 acc[2];
    #pragma unroll
    for (int f = 0; f < 2; f++)
        #pragma unroll
        for (int r = 0; r < 16; r++) acc[f][r] = 0.f;

    bf16x8 wf[2][8];
    WLOAD_(0, 0);

    // staging: 6 halo rows x 2592B. 12 x 1KB gload_lds chunks (3/wave) +
    // 544B/row reg-staged tail (204 uint4 over 256 threads).
    // prologue: stage chunk 0 into buffer 0
    {
        const size_t rowbase = ((size_t)((b * 4 + 0) * 130 + y0) * XCOLS + x0) * XROWB;
        #pragma unroll
        for (int gg = 0; gg < 3; gg++) {
            const int g = wv * 3 + gg;
            const int hy = g >> 1, ii = g & 1;
            __builtin_amdgcn_global_load_lds(
                (const __attribute__((address_space(1))) unsigned*)
                    (xin + rowbase + (size_t)hy * XPITCH + ii * 1024 + lane * 16),
                (__attribute__((address_space(3))) unsigned*)(lds + hy * 2592 + ii * 1024),
                16, 0, 0);
        }
        if (t < 204) {
            const int hy = t / 34;
            const int off = 2048 + (t % 34) * 16;
            uint4 v = *(const uint4*)(xin + rowbase + (size_t)hy * XPITCH + off);
            *(uint4*)(lds + hy * 2592 + off) = v;
        }
    }
    __syncthreads();   // drains vmcnt(0)+lgkmcnt(0): staging complete & visible

    #define TAPX(CH, TAP, CUR, NXT) do {                                      \
        if ((CH) * 9 + (TAP) + 1 < 36) WLOAD_(NXT, (CH) * 9 + (TAP) + 1);     \
        MFMA_TAP_(CUR, ((TAP) / 3) * 2592 + ((TAP) % 3) * 144 + ((CH) & 1) * XLDS_B); \
    } while (0)

    #define CHUNKX(CH, SA, SB) do {                                           \
        uint4 tl0_; bool h0_ = false;                                         \
        const int xd_ = (((CH) + 1) & 1) * XLDS_B;                            \
        if ((CH) < 3) {                                                       \
            const size_t rowb1_ = ((size_t)((b * 4 + (CH) + 1) * 130 + y0) * XCOLS + x0) * XROWB; \
            _Pragma("unroll")                                                 \
            for (int gg = 0; gg < 3; gg++) {                                  \
                const int g = wv * 3 + gg;                                    \
                const int hy = g >> 1, ii = g & 1;                            \
                __builtin_amdgcn_global_load_lds(                             \
                    (const __attribute__((address_space(1))) unsigned*)       \
                        (xin + rowb1_ + (size_t)hy * XPITCH + ii * 1024 + lane * 16), \
                    (__attribute__((address_space(3))) unsigned*)(lds + xd_ + hy * 2592 + ii * 1024), \
                    16, 0, 0);                                                \
            }                                                                 \
            h0_ = (t < 204);                                                  \
            if (h0_) {                                                        \
                const int hy = t / 34, off = 2048 + (t % 34) * 16;            \
                tl0_ = *(const uint4*)(xin + rowb1_ + (size_t)hy * XPITCH + off); \
            }                                                                 \
        }                                                                     \
        TAPX(CH, 0, SA, SB); TAPX(CH, 1, SB, SA); TAPX(CH, 2, SA, SB);        \
        TAPX(CH, 3, SB, SA); TAPX(CH, 4, SA, SB); TAPX(CH, 5, SB, SA);        \
        TAPX(CH, 6, SA, SB); TAPX(CH, 7, SB, SA); TAPX(CH, 8, SA, SB);        \
        if ((CH) < 3) {                                                       \
            if (h0_) {                                                        \
                const int hy = t / 34, off = 2048 + (t % 34) * 16;            \
                *(uint4*)(lds + xd_ + hy * 2592 + off) = tl0_;                \
            }                                                                 \
            __syncthreads();                                                  \
        }                                                                     \
    } while (0)

    CHUNKX(0, 0, 1);
    CHUNKX(1, 1, 0);
    CHUNKX(2, 0, 1);
    CHUNKX(3, 1, 0);

    #undef TAPX
    #undef CHUNKX
    conv_epilogue<RELU, XOUT>(acc, act, bias, outf, outx, Cout, b, x0, y0, wm, wn, kh, l31);
}

// ---------------------------------------------------------------------------
// Direct conv for Cout=2 heads (fp32 input)
// ---------------------------------------------------------------------------
__global__ __launch_bounds__(256) void conv2out_k(
    const float* __restrict__ in, const float* __restrict__ w,
    const float* __restrict__ bias, float* __restrict__ out)
{
    __shared__ float ws[128 * 9 * 2];
    const int t = threadIdx.x;
    for (int i = t; i < 2304; i += 256) {
        const int co = i & 1, tap = (i >> 1) % 9, ci = i / 18;
        ws[i] = w[(size_t)co * 1152 + ci * 9 + tap];
    }
    __syncthreads();

    const int b  = blockIdx.y;
    const int y  = (blockIdx.x >> 3) * 16 + (t >> 4);
    const int x  = (blockIdx.x & 7) * 16 + (t & 15);
    const float* inb = in + (size_t)b * 128 * HW_ + y * 128 + x;

    float a0 = bias[0], a1 = bias[1];
    #pragma unroll 2
    for (int ci = 0; ci < 128; ci++) {
        const float* p  = inb + (size_t)ci * HW_;
        const float* wp = ws + ci * 18;
        #pragma unroll
        for (int tap = 0; tap < 9; tap++) {
            const int dy = tap / 3 - 1, dx = tap % 3 - 1;
            const int yy = y + dy, xx = x + dx;
            float v = 0.f;
            if ((unsigned)yy < 128u && (unsigned)xx < 128u) v = p[dy * 128 + dx];
            a0 = fmaf(v, wp[tap * 2 + 0], a0);
            a1 = fmaf(v, wp[tap * 2 + 1], a1);
        }
    }
    out[((size_t)b * 2 + 0) * HW_ + y * 128 + x] = a0;
    out[((size_t)b * 2 + 1) * HW_ + y * 128 + x] = a1;
}

// ---------------------------------------------------------------------------
// Fused: focal loss + 3x3 NMS (clamped-index max on logits) + hist1.
// ---------------------------------------------------------------------------
__global__ __launch_bounds__(256) void lnh_k(
    const float* __restrict__ L, const float* __restrict__ targets,
    float* __restrict__ loss_out, unsigned* __restrict__ keys,
    unsigned* __restrict__ hist)
{
    __shared__ unsigned h[2048];
    for (int j = threadIdx.x; j < 2048; j += 256) h[j] = 0;
    __syncthreads();

    const int per_b = NCLS_ * HW_;
    const int b = blockIdx.y;
    const float* Lb = L + (size_t)b * per_b;
    const float* Tb = targets + (size_t)b * per_b;
    unsigned* kb = keys + (size_t)b * per_b;

    float sum = 0.f;
    for (int i = blockIdx.x * 256 + threadIdx.x; i < per_b; i += gridDim.x * 256) {
        const float x = Lb[i];
        const float t = Tb[i];
        const float e   = expf(-fabsf(x));
        const float inv = 1.f / (1.f + e);
        const float lp  = log1pf(e);
        const bool  xe  = (x >= 0.f);
        const float p   = xe ? inv : e * inv;       // sigmoid(x)
        const float lsp = xe ? -lp : (x - lp);      // log sigmoid(x)
        const float lsn = lsp - x;                  // log sigmoid(-x)
        float om = 1.f - t;
        float nw = om * om; nw *= nw;
        const float omp = 1.f - p;
        if (t == 1.0f)     sum -= lsp * omp * omp;
        else if (t < 1.0f) sum -= lsn * p * p * nw;

        // 3x3 NMS on logits, clamped indices (duplicates don't change max)
        const int sp = i & (HW_ - 1);
        const int y = sp >> 7, xq = sp & 127;
        const float* plane = Lb + (i - sp);
        const int ym = (y > 0) ? y - 1 : 0,   yp = (y < 127) ? y + 1 : 127;
        const int xm = (xq > 0) ? xq - 1 : 0, xp = (xq < 127) ? xq + 1 : 127;
        const float* r0 = plane + ym * 128;
        const float* r1 = plane + y  * 128;
        const float* r2 = plane + yp * 128;
        float m = fmaxf(fmaxf(fmaxf(r0[xm], r0[xq]), fmaxf(r0[xp], r1[xm])),
                 fmaxf(fmaxf(x, r1[xp]),
                 fmaxf(fmaxf(r2[xm], r2[xq]), r2[xp])));
        const float em   = expf(-fabsf(m));
        const float invm = 1.f / (1.f + em);
        const float pm   = (m >= 0.f) ? invm : em * invm;   // sigmoid(m), same path as p
        const unsigned key = (__float_as_uint(p) == __float_as_uint(pm)) ? __float_as_uint(p) : 0u;
        kb[i] = key;
        if (key) atomicAdd(&h[key >> 21], 1u);
    }

    #pragma unroll
    for (int off = 32; off > 0; off >>= 1) sum += __shfl_down(sum, off, 64);
    __shared__ float wsum[4];
    int lane = threadIdx.x & 63, wid = threadIdx.x >> 6;
    if (lane == 0) wsum[wid] = sum;
    __syncthreads();
    if (threadIdx.x == 0)
        atomicAdd(loss_out, wsum[0] + wsum[1] + wsum[2] + wsum[3]);

    unsigned* gh = hist + b * 2048;
    for (int j = threadIdx.x; j < 2048; j += 256) if (h[j]) atomicAdd(&gh[j], h[j]);
}

// ---------------------------------------------------------------------------
__global__ void hist2_k(const unsigned* __restrict__ keys, const unsigned* __restrict__ bin1,
                        unsigned* __restrict__ hist)
{
    __shared__ unsigned h[2048];
    for (int j = threadIdx.x; j < 2048; j += blockDim.x) h[j] = 0;
    __syncthreads();
    const int per_b = NCLS_ * HW_;
    const int b = blockIdx.y;
    const unsigned b1 = bin1[b];
    const unsigned* kb = keys + (size_t)b * per_b;
    for (int i = blockIdx.x * blockDim.x + threadIdx.x; i < per_b; i += gridDim.x * blockDim.x) {
        unsigned k = kb[i];
        if (k && (k >> 21) == b1) atomicAdd(&h[(k >> 10) & 2047], 1u);
    }
    __syncthreads();
    unsigned* gh = hist + b * 2048;
    for (int j = threadIdx.x; j < 2048; j += blockDim.x) if (h[j]) atomicAdd(&gh[j], h[j]);
}

__global__ void hist3_k(const unsigned* __restrict__ keys, const unsigned* __restrict__ pfx2,
                        unsigned* __restrict__ hist)
{
    __shared__ unsigned h[1024];
    for (int j = threadIdx.x; j < 1024; j += blockDim.x) h[j] = 0;
    __syncthreads();
    const int per_b = NCLS_ * HW_;
    const int b = blockIdx.y;
    const unsigned p2 = pfx2[b];
    const unsigned* kb = keys + (size_t)b * per_b;
    for (int i = blockIdx.x * blockDim.x + threadIdx.x; i < per_b; i += gridDim.x * blockDim.x) {
        unsigned k = kb[i];
        if (k && (k >> 10) == p2) atomicAdd(&h[k & 1023], 1u);
    }
    __syncthreads();
    unsigned* gh = hist + b * 1024;
    for (int j = threadIdx.x; j < 1024; j += blockDim.x) if (h[j]) atomicAdd(&gh[j], h[j]);
}

// ---------------------------------------------------------------------------
template<int NBINS, int LEVEL>
__global__ __launch_bounds__(256) void scan_k(
    const unsigned* __restrict__ hist,
    const unsigned* __restrict__ inPfx, const unsigned* __restrict__ inGt,
    unsigned* __restrict__ outPfx, unsigned* __restrict__ outGt)
{
    constexpr int PER = NBINS / 256;
    const int b = blockIdx.x;
    const int t = threadIdx.x;
    const unsigned* h = hist + b * NBINS;
    const unsigned base = (LEVEL == 1) ? 0u : inGt[b];

    unsigned v[PER];
    unsigned local = 0;
    #pragma unroll
    for (int i = 0; i < PER; i++) { v[i] = h[t * PER + i]; local += v[i]; }

    __shared__ unsigned ps[256];
    ps[t] = local;
    __syncthreads();
    #pragma unroll
    for (int off = 1; off < 256; off <<= 1) {
        unsigned add = (t + off < 256) ? ps[t + off] : 0u;
        __syncthreads();
        ps[t] += add;
        __syncthreads();
    }
    const unsigned sumAbove = (t == 255) ? 0u : ps[t + 1];

    unsigned sfx = sumAbove;
    #pragma unroll
    for (int i = PER - 1; i >= 0; i--) {
        unsigned sfx_next = sfx;
        sfx += v[i];
        bool cond     = (base + sfx      >= KTOP);
        bool condNext = (base + sfx_next >= KTOP);
        if (cond && !condNext) {
            unsigned sel = (unsigned)(t * PER + i);
            unsigned pfx = (LEVEL == 1) ? sel
                         : (LEVEL == 2) ? ((inPfx[b] << 11) | sel)
                                        : ((inPfx[b] << 10) | sel);
            outPfx[b] = pfx;
            outGt[b]  = base + sfx_next;
        }
    }
    if (t == 0 && base + ps[0] < KTOP) {
        unsigned pfx = (LEVEL == 1) ? 0u
                     : (LEVEL == 2) ? (inPfx[b] << 11)
                                    : (inPfx[b] << 10);
        outPfx[b] = pfx;
        outGt[b]  = base + ps[0];
    }
}

// ---------------------------------------------------------------------------
__global__ void select_k(const unsigned* __restrict__ keys, const unsigned* __restrict__ Tk,
                         unsigned* cntA, unsigned* cntB,
                         uint2* __restrict__ listA, unsigned* __restrict__ listB)
{
    const int per_b = NCLS_ * HW_;
    const int b = blockIdx.y;
    const unsigned T = Tk[b];
    const unsigned* kb = keys + (size_t)b * per_b;
    for (int i = blockIdx.x * blockDim.x + threadIdx.x; i < per_b; i += gridDim.x * blockDim.x) {
        unsigned k = kb[i];
        if (k > T) {
            unsigned pos = atomicAdd(&cntA[b], 1u);
            if (pos < KTOP) listA[b * KTOP + pos] = make_uint2(k, (unsigned)i);
        } else if (k == T && k != 0u) {
            unsigned pos = atomicAdd(&cntB[b], 1u);
            if (pos < CAPB) listB[b * CAPB + pos] = (unsigned)i;
        }
    }
}

// ---------------------------------------------------------------------------
__global__ void finalize_k(const unsigned* __restrict__ cntA, const unsigned* __restrict__ cntB,
                           const uint2* __restrict__ listA, const unsigned* __restrict__ listB,
                           const unsigned* __restrict__ Tk,
                           const float* __restrict__ wh, const float* __restrict__ off,
                           float* __restrict__ out)
{
    __shared__ unsigned sk[KTOP], si[KTOP], ok[KTOP], oi[KTOP];
    const int b = blockIdx.x;
    const int nA = (int)min(cntA[b], (unsigned)KTOP);
    const unsigned T = Tk[b];

    if ((int)threadIdx.x < nA) {
        uint2 e = listA[b * KTOP + threadIdx.x];
        sk[threadIdx.x] = e.x;
        si[threadIdx.x] = e.y;
    }
    __syncthreads();

    if (threadIdx.x == 0) {
        int need = KTOP - nA;
        unsigned nB = min(cntB[b], (unsigned)CAPB);
        long long prev = -1;
        for (int r = 0; r < need; r++) {
            unsigned best = 0xFFFFFFFFu;
            for (unsigned j = 0; j < nB; j++) {
                unsigned idx = listB[b * CAPB + j];
                if ((long long)idx > prev && idx < best) best = idx;
            }
            if (best == 0xFFFFFFFFu) { sk[nA + r] = 0u; si[nA + r] = 0u; }
            else { sk[nA + r] = T; si[nA + r] = best; prev = (long long)best; }
        }
    }
    __syncthreads();

    if (threadIdx.x < KTOP) {
        unsigned kk = sk[threadIdx.x], ii = si[threadIdx.x];
        int rank = 0;
        for (int j = 0; j < KTOP; j++) {
            unsigned kj = sk[j], ij = si[j];
            rank += (kj > kk) || (kj == kk && ij < ii);
        }
        ok[rank] = kk; oi[rank] = ii;
    }
    __syncthreads();

    if (threadIdx.x < KTOP) {
        int r = threadIdx.x;
        unsigned ind = oi[r];
        float score = __uint_as_float(ok[r]);
        int cls = (int)(ind / HW_);
        int sp  = (int)(ind % HW_);
        float ysf = (float)(sp >> 7);
        float xsf = (float)(sp & 127);
        float w0 = wh[((size_t)b * 2 + 0) * HW_ + sp];
        float h0 = wh[((size_t)b * 2 + 1) * HW_ + sp];
        float o0 = off[((size_t)b * 2 + 0) * HW_ + sp];
        float o1 = off[((size_t)b * 2 + 1) * HW_ + sp];
        float cx = xsf + o0;
        float cy = ysf + o1;
        float* boxes  = out;
        float* scores = out + (size_t)B_ * KTOP * 4;
        float* clses  = out + (size_t)B_ * KTOP * 5;
        boxes[((size_t)b * KTOP + r) * 4 + 0] = cx - w0 * 0.5f;
        boxes[((size_t)b * KTOP + r) * 4 + 1] = cy - h0 * 0.5f;
        boxes[((size_t)b * KTOP + r) * 4 + 2] = cx + w0 * 0.5f;
        boxes[((size_t)b * KTOP + r) * 4 + 3] = cy + h0 * 0.5f;
        scores[b * KTOP + r] = score;
        clses[b * KTOP + r]  = (float)cls;
    }
}

// ---------------------------------------------------------------------------
extern "C" void kernel_launch(void* const* d_in, const int* in_sizes, int n_in,
                              void* d_out, int out_size, void* d_ws, size_t ws_size,
                              hipStream_t stream)
{
    const float* feature      = (const float*)d_in[0];
    const float* targets      = (const float*)d_in[1];
    const float* cls_w        = (const float*)d_in[2];
    const float* cls_b        = (const float*)d_in[3];
    const float* bbox_w       = (const float*)d_in[4];
    const float* bbox_b       = (const float*)d_in[5];
    const float* off_w        = (const float*)d_in[6];
    const float* off_b        = (const float*)d_in[7];
    const float* cls_score_w  = (const float*)d_in[8];
    const float* cls_score_b  = (const float*)d_in[9];
    const float* bbox_pred_w  = (const float*)d_in[10];
    const float* bbox_pred_b  = (const float*)d_in[11];
    const float* center_off_w = (const float*)d_in[12];
    const float* center_off_b = (const float*)d_in[13];
    float* out = (float*)d_out;

    const size_t L_BYTES  = (size_t)B_ * NCLS_ * HW_ * 4;    // 21 MB
    const size_t P_BYTES  = (size_t)B_ * 2 * HW_ * 4;        // 0.5 MB
    const size_t WT_BYTES = (size_t)NIMG * WIMG_B;           // 4.1 MB

    char* ws = (char*)d_ws;
    const size_t lw = (size_t)C_ * C_ * 9;
    float* loss_ptr = out + (size_t)B_ * KTOP * 6;

    // layout: XA | XB(=Bf=keys) | L | WH | OFF | WT | sm   (~105 MB total)
    char* XA = ws;
    char* XB = ws + XSZ;
    float* L   = (float*)(ws + 2 * XSZ);
    float* WH  = (float*)(ws + 2 * XSZ + L_BYTES);
    float* OFF = (float*)(ws + 2 * XSZ + L_BYTES + P_BYTES);
    unsigned short* WT = (unsigned short*)(ws + 2 * XSZ + L_BYTES + 2 * P_BYTES);
    unsigned* sm = (unsigned*)(ws + 2 * XSZ + L_BYTES + 2 * P_BYTES + WT_BYTES);
    float* Bf = (float*)XB;
    unsigned* keys = (unsigned*)XB;

    unsigned* hist1 = sm;
    unsigned* hist2 = sm + 4 * 2048;
    unsigned* hist3 = sm + 8 * 2048;
    unsigned* bin1  = sm + 8 * 2048 + 4 * 1024;
    unsigned* gt1   = bin1 + 4;
    unsigned* pfx2  = bin1 + 8;
    unsigned* gt2   = bin1 + 12;
    unsigned* Tk    = bin1 + 16;
    unsigned* gt3   = bin1 + 20;
    unsigned* cntA  = bin1 + 24;
    unsigned* cntB  = bin1 + 28;
    uint2*    listA = (uint2*)(bin1 + 32);
    unsigned* listB = (unsigned*)(bin1 + 32 + 2 * B_ * KTOP);

    WtArgs wa;
    wa.src[0] = cls_w;        wa.cout[0] = 128;
    wa.src[1] = bbox_w;       wa.cout[1] = 128;
    wa.src[2] = off_w;        wa.cout[2] = 128;
    wa.src[3] = cls_w + lw;   wa.cout[3] = 128;
    wa.src[4] = bbox_w + lw;  wa.cout[4] = 128;
    wa.src[5] = off_w + lw;   wa.cout[5] = 128;
    wa.src[6] = cls_score_w;  wa.cout[6] = NCLS_;

    init_k<<<145, 256, 0, stream>>>(XA, XB, sm, loss_ptr);
    wtx_k<<<dim3(72, 1, NIMG), 256, 0, stream>>>(wa, WT);

    #define WIMG(i) (WT + (size_t)(i) * (WIMG_B / 2))

    // cls tower -> logits L
    conv_f_k<1, 1><<<1024, 256, 0, stream>>>(feature, WIMG(0), cls_b,       nullptr, XA, 128);
    conv_x_k<1, 1><<<1024, 256, 0, stream>>>(XA,      WIMG(3), cls_b + C_,  nullptr, XB, 128);
    conv_x_k<0, 0><<<1024, 256, 0, stream>>>(XB,      WIMG(6), cls_score_b, L, nullptr, NCLS_);
    // bbox tower -> WH
    conv_f_k<1, 1><<<1024, 256, 0, stream>>>(feature, WIMG(1), bbox_b,      nullptr, XA, 128);
    conv_x_k<1, 0><<<1024, 256, 0, stream>>>(XA,      WIMG(4), bbox_b + C_, Bf, nullptr, 128);
    conv2out_k<<<dim3(64, 4), 256, 0, stream>>>(Bf, bbox_pred_w, bbox_pred_b, WH);
    // off tower -> OFF
    conv_f_k<1, 1><<<1024, 256, 0, stream>>>(feature, WIMG(2), off_b,       nullptr, XA, 128);
    conv_x_k<1, 0><<<1024, 256, 0, stream>>>(XA,      WIMG(5), off_b + C_,  Bf, nullptr, 128);
    conv2out_k<<<dim3(64, 4), 256, 0, stream>>>(Bf, center_off_w, center_off_b, OFF);

    lnh_k<<<dim3(512, B_), 256, 0, stream>>>(L, targets, loss_ptr, keys, hist1);

    dim3 hgrid(512, B_);
    scan_k<2048, 1><<<B_, 256, 0, stream>>>(hist1, nullptr, nullptr, bin1, gt1);
    hist2_k<<<hgrid, 256, 0, stream>>>(keys, bin1, hist2);
    scan_k<2048, 2><<<B_, 256, 0, stream>>>(hist2, bin1, gt1, pfx2, gt2);
    hist3_k<<<hgrid, 256, 0, stream>>>(keys, pfx2, hist3);
    scan_k<1024, 3><<<B_, 256, 0, stream>>>(hist3, pfx2, gt2, Tk, gt3);
    select_k<<<hgrid, 256, 0, stream>>>(keys, Tk, cntA, cntB, listA, listB);

    finalize_k<<<B_, 128, 0, stream>>>(cntA, cntB, listA, listB, Tk, WH, OFF, out);
}

// Round 7
// 577.383 us; speedup vs baseline: 2.6633x; 2.6633x over previous
//
#include <hip/hip_runtime.h>
#include <hip/hip_bf16.h>
#include <math.h>

#define B_    4
#define C_    128
#define H_    128
#define W_    128
#define HW_   (H_*W_)
#define NCLS_ 80
#define KTOP  100
#define CAPB  2048

typedef __attribute__((ext_vector_type(8)))  short bf16x8;
typedef __attribute__((ext_vector_type(16))) float f32x16;

// W image (register-load layout): per conv 36 stages of 16KB:
//   stage s = chunk*9+tap : [g 4][ks 2][part 2][32 couts x 32B]
//   lane l reads 16B at ((l&31)*32 + (l>>5)*16) -> row l31, k-half kh
#define WSTG_B     16384
#define WIMG_B     589824           // 36*16384
#define NIMG       7
// X'' image: [b*4+chunk] x [row 0..129] x [col 0..129] x 144B
#define XROWB      144
#define XCOLS      130
#define XPITCH     (XCOLS * XROWB)              // 18720
#define XSZ        ((size_t)16 * 130 * XPITCH)  // 38,937,600 per buffer
#define XLDS_B     25920                        // one X tile: 180 pos * 144B
#define LDS_TOT    (2 * XLDS_B)                 // 51840 (double-buffered X)
#define ZERO_N     20512                        // hists + scalars

__device__ __forceinline__ unsigned bf16_rne(float x) {
    unsigned u = __float_as_uint(x);
    return (u + 0x7FFFu + ((u >> 16) & 1u)) >> 16;
}
__device__ __forceinline__ void split2(float v0, float v1, unsigned& hiP, unsigned& loP) {
    unsigned h0 = bf16_rne(v0), h1 = bf16_rne(v1);
    float r0 = v0 - __uint_as_float(h0 << 16);
    float r1 = v1 - __uint_as_float(h1 << 16);
    unsigned l0 = bf16_rne(r0), l1 = bf16_rne(r1);
    hiP = h0 | (h1 << 16);
    loP = l0 | (l1 << 16);
}

#define MFMA32(a, bvec, c) __builtin_amdgcn_mfma_f32_32x32x16_bf16(a, bvec, c, 0, 0, 0)

// ---------------------------------------------------------------------------
// init: X'' borders (both buffers) + small scratch + loss slot
// ---------------------------------------------------------------------------
__global__ __launch_bounds__(256) void init_k(char* __restrict__ xa, char* __restrict__ xb,
                                              unsigned* __restrict__ sm, float* __restrict__ loss)
{
    const int i = blockIdx.x * 256 + threadIdx.x;
    if (i < 16512) {
        char* buf = (i < 8256) ? xa : xb;
        const int j = (i < 8256) ? i : i - 8256;
        int R, col;
        if (j < 4160) {
            const int g = j / 260, rr = j % 260;
            R = g * 130 + ((rr < 130) ? 0 : 129);
            col = rr % 130;
        } else {
            const int q = j - 4160;
            const int g = q / 256, m = q % 256;
            R = g * 130 + 1 + (m >> 1);
            col = (m & 1) ? 129 : 0;
        }
        char* p = buf + ((size_t)R * XCOLS + col) * XROWB;
        #pragma unroll
        for (int k = 0; k < 9; k++) *(uint4*)(p + k * 16) = make_uint4(0, 0, 0, 0);
    } else {
        const int k = i - 16512;
        if (k < ZERO_N) sm[k] = 0u;
        if (k == ZERO_N) *loss = 0.f;
    }
}

// ---------------------------------------------------------------------------
// Weight transform into the register-load layout.
// Images: 0=clsL1 1=bboxL1 2=offL1 3=clsL2 4=bboxL2 5=offL2 6=score
// ---------------------------------------------------------------------------
struct WtArgs { const float* src[NIMG]; int cout[NIMG]; };

__global__ __launch_bounds__(256) void wtx_k(WtArgs a, unsigned short* wt)
{
    const int img = blockIdx.z;
    const int idx = blockIdx.x * 256 + threadIdx.x;   // < 18432
    const int h  = idx & 1;
    const int ks = (idx >> 1) & 1;
    const int r  = (idx >> 2) & 31;
    const int g  = (idx >> 7) & 3;
    const int st = idx >> 9;
    if (st >= 36) return;
    const int tap = st % 9, chunk = st / 9;
    const float* w = a.src[img];
    const int Cout = a.cout[img];
    const int cout = g * 32 + r;
    const int cin0 = chunk * 32 + ks * 16 + h * 8;
    float v[8];
    #pragma unroll
    for (int j = 0; j < 8; j++)
        v[j] = (cout < Cout) ? w[((size_t)cout * 128 + cin0 + j) * 9 + tap] : 0.f;
    unsigned hiW[4], loW[4];
    #pragma unroll
    for (int j = 0; j < 4; j++) split2(v[2 * j], v[2 * j + 1], hiW[j], loW[j]);
    char* dst = (char*)wt + (size_t)img * WIMG_B + (size_t)st * WSTG_B
              + g * 4096 + ks * 2048 + r * 32 + h * 16;
    *(uint4*)dst          = make_uint4(hiW[0], hiW[1], hiW[2], hiW[3]);
    *(uint4*)(dst + 1024) = make_uint4(loW[0], loW[1], loW[2], loW[3]);
}

// ---------------------------------------------------------------------------
// Shared epilogue: write fp32 (XOUT=0) or X'' hi/lo (XOUT=1)
// ---------------------------------------------------------------------------
template<int RELU, int XOUT>
__device__ __forceinline__ void conv_epilogue(
    f32x16 (&acc)[2][2], const bool* act,
    const float* bias, float* outf, char* outx, int Cout,
    int b, int x0, int y0, int wm, int wn, int kh, int l31)
{
    #pragma unroll
    for (int f = 0; f < 2; f++) {
        if (!act[f]) continue;
        if (XOUT == 0) {
            #pragma unroll
            for (int r = 0; r < 16; r++) {
                const int co = wm * 64 + f * 32 + 4 * kh + (r & 3) + 8 * (r >> 2);
                if (co < Cout) {
                    const float bv = bias[co];
                    #pragma unroll
                    for (int fn = 0; fn < 2; fn++) {
                        const int p = wn * 64 + fn * 32 + l31;
                        float v = acc[f][fn][r] + bv;
                        if (RELU) v = fmaxf(v, 0.f);
                        outf[((size_t)b * Cout + co) * HW_ + (size_t)(y0 + (p >> 4)) * 128 + (x0 + (p & 15))] = v;
                    }
                }
            }
        } else {
            const int chunkO = wm * 2 + f;
            #pragma unroll
            for (int r2 = 0; r2 < 8; r2++) {
                const int r = 2 * r2;
                const int cij = 4 * kh + (r & 3) + 8 * (r >> 2);
                const int co0 = wm * 64 + f * 32 + cij;
                const float b0v = bias[co0], b1v = bias[co0 + 1];
                #pragma unroll
                for (int fn = 0; fn < 2; fn++) {
                    const int p = wn * 64 + fn * 32 + l31;
                    float v0 = acc[f][fn][r] + b0v;
                    float v1 = acc[f][fn][r + 1] + b1v;
                    if (RELU) { v0 = fmaxf(v0, 0.f); v1 = fmaxf(v1, 0.f); }
                    unsigned hiP, loP; split2(v0, v1, hiP, loP);
                    char* rowp = outx + ((size_t)((b * 4 + chunkO) * 130 + (y0 + (p >> 4) + 1)) * XCOLS
                                        + (x0 + (p & 15) + 1)) * XROWB;
                    *(unsigned*)(rowp + 2 * cij)      = hiP;
                    *(unsigned*)(rowp + 64 + 2 * cij) = loP;
                }
            }
        }
    }
}

// W prefetch: honest 2-slot rotation; slot = 8 bf16x8 (32 VGPR). All slot
// indices compile-time literals via chunk-unrolled macros (rule #20).
#define WLOAD_(SLOT, SIDX) do {                                               \
    const char* wp_ = wb + (size_t)(SIDX) * WSTG_B;                           \
    _Pragma("unroll")                                                         \
    for (int f_ = 0; f_ < 2; f_++) {                                          \
        _Pragma("unroll")                                                     \
        for (int k_ = 0; k_ < 2; k_++) {                                      \
            wf[SLOT][f_ * 2 + k_]     = *(const bf16x8*)(wp_ + f_ * 4096 + k_ * 2048);        \
            wf[SLOT][4 + f_ * 2 + k_] = *(const bf16x8*)(wp_ + f_ * 4096 + k_ * 2048 + 1024); \
        }                                                                     \
    }                                                                         \
} while (0)

#define MFMA_TAP_(CUR, DOFF) do {                                             \
    _Pragma("unroll")                                                         \
    for (int ks = 0; ks < 2; ks++) {                                          \
        bf16x8 bh[2], bl[2];                                                  \
        _Pragma("unroll")                                                     \
        for (int fn = 0; fn < 2; fn++) {                                      \
            bh[fn] = *(const bf16x8*)(lds + baddr[fn] + (DOFF) + ks * 32);      \
            bl[fn] = *(const bf16x8*)(lds + baddr[fn] + (DOFF) + ks * 32 + 64); \
        }                                                                     \
        _Pragma("unroll")                                                     \
        for (int f = 0; f < 2; f++) if (act[f]) {                             \
            _Pragma("unroll")                                                 \
            for (int fn = 0; fn < 2; fn++)                                    \
                acc[f][fn] = MFMA32(wf[CUR][f * 2 + ks], bh[fn], acc[f][fn]); \
        }                                                                     \
        _Pragma("unroll")                                                     \
        for (int f = 0; f < 2; f++) if (act[f]) {                             \
            _Pragma("unroll")                                                 \
            for (int fn = 0; fn < 2; fn++)                                    \
                acc[f][fn] = MFMA32(wf[CUR][f * 2 + ks], bl[fn], acc[f][fn]); \
        }                                                                     \
        _Pragma("unroll")                                                     \
        for (int f = 0; f < 2; f++) if (act[f]) {                             \
            _Pragma("unroll")                                                 \
            for (int fn = 0; fn < 2; fn++)                                    \
                acc[f][fn] = MFMA32(wf[CUR][4 + f * 2 + ks], bh[fn], acc[f][fn]); \
        }                                                                     \
    }                                                                         \
} while (0)

// ---------------------------------------------------------------------------
// MFMA conv, fp32 input. R2-champion geometry: 4 waves, wave = 64 couts x
// 64 px. W direct global->reg with literal 2-slot prefetch; X double-buffered
// in LDS. One __syncthreads per chunk.
// ---------------------------------------------------------------------------
template<int RELU, int XOUT>
__global__ __launch_bounds__(256, 2) void conv_f_k(
    const float* __restrict__ in, const unsigned short* __restrict__ wt,
    const float* __restrict__ bias, float* __restrict__ outf,
    char* __restrict__ outx, int Cout)
{
    __shared__ __align__(16) char lds[LDS_TOT];

    const int t    = threadIdx.x;
    const int lane = t & 63;
    const int wv   = t >> 6;
    const int wm   = wv >> 1;
    const int wn   = wv & 1;
    const int l31  = lane & 31;
    const int kh   = lane >> 5;

    const int bi = blockIdx.x;
    const int x0 = (bi & 7) << 4;
    const int y0 = ((bi >> 3) & 15) << 3;
    const int b  = bi >> 7;

    int baddr[2];
    #pragma unroll
    for (int fn = 0; fn < 2; fn++) {
        const int p = wn * 64 + fn * 32 + l31;
        baddr[fn] = ((p >> 4) * 18 + (p & 15)) * 144 + kh * 16;
    }
    bool act[2];
    #pragma unroll
    for (int f = 0; f < 2; f++) act[f] = (wm * 64 + f * 32) < Cout;

    const int wlane = ((lane & 31) << 5) | (kh << 4);
    const char* wb = (const char*)wt + wm * 8192 + wlane;

    f32x16 acc[2][2];
    #pragma unroll
    for (int i = 0; i < 2; i++)
        #pragma unroll
        for (int j = 0; j < 2; j++)
            #pragma unroll
            for (int r = 0; r < 16; r++) acc[i][j][r] = 0.f;

    const float* inb = in + (size_t)b * 128 * HW_;

    bf16x8 wf[2][8];
    WLOAD_(0, 0);                       // prologue: tap 0 W in flight early

    float xa[12], xb[12];
    #define LOADX(ch) do {                                                    \
        _Pragma("unroll")                                                     \
        for (int it = 0; it < 12; it++) {                                     \
            const int idx = t + it * 256;                                     \
            const int pl = idx & 15, cp = (idx >> 4) & 15, ph = idx >> 8;     \
            const int pos = ph * 16 + pl;                                     \
            float v0 = 0.f, v1 = 0.f;                                         \
            if (pos < 180) {                                                  \
                const int hy = pos / 18, hx = pos - hy * 18;                  \
                const int gy = y0 - 1 + hy, gx = x0 - 1 + hx;                 \
                if ((unsigned)gy < 128u && (unsigned)gx < 128u) {             \
                    const float* p0 = inb + (size_t)((ch) * 32 + 2 * cp) * HW_ \
                                          + gy * 128 + gx;                    \
                    v0 = p0[0]; v1 = p0[HW_];                                 \
                }                                                             \
            }                                                                 \
            xa[it] = v0; xb[it] = v1;                                         \
        }                                                                     \
    } while (0)

    #define STOREX(bufsel) do {                                               \
        _Pragma("unroll")                                                     \
        for (int it = 0; it < 12; it++) {                                     \
            const int idx = t + it * 256;                                     \
            const int pl = idx & 15, cp = (idx >> 4) & 15, ph = idx >> 8;     \
            const int pos = ph * 16 + pl;                                     \
            if (pos < 180) {                                                  \
                unsigned hiP, loP; split2(xa[it], xb[it], hiP, loP);          \
                *(unsigned*)(lds + (bufsel) * XLDS_B + pos * 144 + 4 * cp)      = hiP; \
                *(unsigned*)(lds + (bufsel) * XLDS_B + pos * 144 + 64 + 4 * cp) = loP; \
            }                                                                 \
        }                                                                     \
    } while (0)

    // prologue: stage chunk 0 into buffer 0
    LOADX(0);
    STOREX(0);
    __syncthreads();

    #define TAPF(CH, TAP, CUR, NXT) do {                                      \
        if ((CH) * 9 + (TAP) + 1 < 36) WLOAD_(NXT, (CH) * 9 + (TAP) + 1);     \
        MFMA_TAP_(CUR, (((TAP) / 3) * 18 + ((TAP) % 3)) * 144 + ((CH) & 1) * XLDS_B); \
    } while (0)

    #define CHUNKF(CH, SA, SB) do {                                           \
        TAPF(CH, 0, SA, SB); TAPF(CH, 1, SB, SA); TAPF(CH, 2, SA, SB);        \
        TAPF(CH, 3, SB, SA); TAPF(CH, 4, SA, SB); TAPF(CH, 5, SB, SA);        \
        if ((CH) < 3) LOADX((CH) + 1);                                        \
        TAPF(CH, 6, SA, SB); TAPF(CH, 7, SB, SA); TAPF(CH, 8, SA, SB);        \
        if ((CH) < 3) { STOREX(((CH) + 1) & 1); __syncthreads(); }            \
    } while (0)

    CHUNKF(0, 0, 1);
    CHUNKF(1, 1, 0);
    CHUNKF(2, 0, 1);
    CHUNKF(3, 1, 0);

    #undef LOADX
    #undef STOREX
    #undef TAPF
    #undef CHUNKF
    conv_epilogue<RELU, XOUT>(acc, act, bias, outf, outx, Cout, b, x0, y0, wm, wn, kh, l31);
}

// ---------------------------------------------------------------------------
// MFMA conv, X'' input. R2-champion geometry + literal 2-slot W prefetch.
// X double-buffered in LDS via global_load_lds (+ reg-staged tail).
// ---------------------------------------------------------------------------
template<int RELU, int XOUT>
__global__ __launch_bounds__(256, 2) void conv_x_k(
    const char* __restrict__ xin, const unsigned short* __restrict__ wt,
    const float* __restrict__ bias, float* __restrict__ outf,
    char* __restrict__ outx, int Cout)
{
    __shared__ __align__(16) char lds[LDS_TOT];

    const int t    = threadIdx.x;
    const int lane = t & 63;
    const int wv   = t >> 6;
    const int wm   = wv >> 1;
    const int wn   = wv & 1;
    const int l31  = lane & 31;
    const int kh   = lane >> 5;

    const int bi = blockIdx.x;
    const int x0 = (bi & 7) << 4;
    const int y0 = ((bi >> 3) & 15) << 3;
    const int b  = bi >> 7;

    int baddr[2];
    #pragma unroll
    for (int fn = 0; fn < 2; fn++) {
        const int p = wn * 64 + fn * 32 + l31;
        baddr[fn] = (p >> 4) * 2592 + (p & 15) * 144 + kh * 16;
    }
    bool act[2];
    #pragma unroll
    for (int f = 0; f < 2; f++) act[f] = (wm * 64 + f * 32) < Cout;

    const int wlane = ((lane & 31) << 5) | (kh << 4);
    const char* wb = (const char*)wt + wm * 8192 + wlane;

    f32x16 acc[2][2];
    #pragma unroll
    for (int i = 0; i < 2; i++)
        #pragma unroll
        for (int j = 0; j < 2; j++)
            #pragma unroll
            for (int r = 0; r < 16; r++) acc[i][j][r] = 0.f;

    bf16x8 wf[2][8];
    WLOAD_(0, 0);                       // prologue: tap 0 W in flight early

    // prologue: stage chunk 0 into buffer 0
    {
        const size_t rowbase = ((size_t)((b * 4 + 0) * 130 + y0) * XCOLS + x0) * XROWB;
        #pragma unroll
        for (int gg = 0; gg < 5; gg++) {
            const int g = wv * 5 + gg;
            const int hy = g >> 1, i = g & 1;
            __builtin_amdgcn_global_load_lds(
                (const __attribute__((address_space(1))) unsigned*)
                    (xin + rowbase + (size_t)hy * XPITCH + i * 1024 + lane * 16),
                (__attribute__((address_space(3))) unsigned*)(lds + hy * 2592 + i * 1024),
                16, 0, 0);
        }
        for (int u = t; u < 340; u += 256) {
            const int hy = u / 34;
            const int off = 2048 + (u % 34) * 16;
            uint4 v = *(const uint4*)(xin + rowbase + (size_t)hy * XPITCH + off);
            *(uint4*)(lds + hy * 2592 + off) = v;
        }
    }
    __syncthreads();   // drains vmcnt(0)+lgkmcnt(0): staging complete & visible

    #define TAPX(CH, TAP, CUR, NXT) do {                                      \
        if ((CH) * 9 + (TAP) + 1 < 36) WLOAD_(NXT, (CH) * 9 + (TAP) + 1);     \
        MFMA_TAP_(CUR, ((TAP) / 3) * 2592 + ((TAP) % 3) * 144 + ((CH) & 1) * XLDS_B); \
    } while (0)

    #define CHUNKX(CH, SA, SB) do {                                           \
        uint4 tl0_, tl1_; bool h1_ = false;                                   \
        const int xd_ = (((CH) + 1) & 1) * XLDS_B;                            \
        if ((CH) < 3) {                                                       \
            const size_t rowb1_ = ((size_t)((b * 4 + (CH) + 1) * 130 + y0) * XCOLS + x0) * XROWB; \
            _Pragma("unroll")                                                 \
            for (int gg = 0; gg < 5; gg++) {                                  \
                const int g = wv * 5 + gg;                                    \
                const int hy = g >> 1, ii = g & 1;                            \
                __builtin_amdgcn_global_load_lds(                             \
                    (const __attribute__((address_space(1))) unsigned*)       \
                        (xin + rowb1_ + (size_t)hy * XPITCH + ii * 1024 + lane * 16), \
                    (__attribute__((address_space(3))) unsigned*)(lds + xd_ + hy * 2592 + ii * 1024), \
                    16, 0, 0);                                                \
            }                                                                 \
            {                                                                 \
                const int hy = t / 34, off = 2048 + (t % 34) * 16;            \
                tl0_ = *(const uint4*)(xin + rowb1_ + (size_t)hy * XPITCH + off); \
            }                                                                 \
            h1_ = (t < 84);                                                   \
            if (h1_) {                                                        \
                const int u = t + 256;                                        \
                const int hy = u / 34, off = 2048 + (u % 34) * 16;            \
                tl1_ = *(const uint4*)(xin + rowb1_ + (size_t)hy * XPITCH + off); \
            }                                                                 \
        }                                                                     \
        TAPX(CH, 0, SA, SB); TAPX(CH, 1, SB, SA); TAPX(CH, 2, SA, SB);        \
        TAPX(CH, 3, SB, SA); TAPX(CH, 4, SA, SB); TAPX(CH, 5, SB, SA);        \
        TAPX(CH, 6, SA, SB); TAPX(CH, 7, SB, SA); TAPX(CH, 8, SA, SB);        \
        if ((CH) < 3) {                                                       \
            {                                                                 \
                const int hy = t / 34, off = 2048 + (t % 34) * 16;            \
                *(uint4*)(lds + xd_ + hy * 2592 + off) = tl0_;                \
            }                                                                 \
            if (h1_) {                                                        \
                const int u = t + 256;                                        \
                const int hy = u / 34, off = 2048 + (u % 34) * 16;            \
                *(uint4*)(lds + xd_ + hy * 2592 + off) = tl1_;                \
            }                                                                 \
            __syncthreads();                                                  \
        }                                                                     \
    } while (0)

    CHUNKX(0, 0, 1);
    CHUNKX(1, 1, 0);
    CHUNKX(2, 0, 1);
    CHUNKX(3, 1, 0);

    #undef TAPX
    #undef CHUNKX
    conv_epilogue<RELU, XOUT>(acc, act, bias, outf, outx, Cout, b, x0, y0, wm, wn, kh, l31);
}

// ---------------------------------------------------------------------------
// Direct conv for Cout=2 heads (fp32 input)
// ---------------------------------------------------------------------------
__global__ __launch_bounds__(256) void conv2out_k(
    const float* __restrict__ in, const float* __restrict__ w,
    const float* __restrict__ bias, float* __restrict__ out)
{
    __shared__ float ws[128 * 9 * 2];
    const int t = threadIdx.x;
    for (int i = t; i < 2304; i += 256) {
        const int co = i & 1, tap = (i >> 1) % 9, ci = i / 18;
        ws[i] = w[(size_t)co * 1152 + ci * 9 + tap];
    }
    __syncthreads();

    const int b  = blockIdx.y;
    const int y  = (blockIdx.x >> 3) * 16 + (t >> 4);
    const int x  = (blockIdx.x & 7) * 16 + (t & 15);
    const float* inb = in + (size_t)b * 128 * HW_ + y * 128 + x;

    float a0 = bias[0], a1 = bias[1];
    #pragma unroll 2
    for (int ci = 0; ci < 128; ci++) {
        const float* p  = inb + (size_t)ci * HW_;
        const float* wp = ws + ci * 18;
        #pragma unroll
        for (int tap = 0; tap < 9; tap++) {
            const int dy = tap / 3 - 1, dx = tap % 3 - 1;
            const int yy = y + dy, xx = x + dx;
            float v = 0.f;
            if ((unsigned)yy < 128u && (unsigned)xx < 128u) v = p[dy * 128 + dx];
            a0 = fmaf(v, wp[tap * 2 + 0], a0);
            a1 = fmaf(v, wp[tap * 2 + 1], a1);
        }
    }
    out[((size_t)b * 2 + 0) * HW_ + y * 128 + x] = a0;
    out[((size_t)b * 2 + 1) * HW_ + y * 128 + x] = a1;
}

// ---------------------------------------------------------------------------
// Fused: focal loss + 3x3 NMS (clamped-index max on logits) + hist1.
// ---------------------------------------------------------------------------
__global__ __launch_bounds__(256) void lnh_k(
    const float* __restrict__ L, const float* __restrict__ targets,
    float* __restrict__ loss_out, unsigned* __restrict__ keys,
    unsigned* __restrict__ hist)
{
    __shared__ unsigned h[2048];
    for (int j = threadIdx.x; j < 2048; j += 256) h[j] = 0;
    __syncthreads();

    const int per_b = NCLS_ * HW_;
    const int b = blockIdx.y;
    const float* Lb = L + (size_t)b * per_b;
    const float* Tb = targets + (size_t)b * per_b;
    unsigned* kb = keys + (size_t)b * per_b;

    float sum = 0.f;
    for (int i = blockIdx.x * 256 + threadIdx.x; i < per_b; i += gridDim.x * 256) {
        const float x = Lb[i];
        const float t = Tb[i];
        const float e   = expf(-fabsf(x));
        const float inv = 1.f / (1.f + e);
        const float lp  = log1pf(e);
        const bool  xe  = (x >= 0.f);
        const float p   = xe ? inv : e * inv;       // sigmoid(x)
        const float lsp = xe ? -lp : (x - lp);      // log sigmoid(x)
        const float lsn = lsp - x;                  // log sigmoid(-x)
        float om = 1.f - t;
        float nw = om * om; nw *= nw;
        const float omp = 1.f - p;
        if (t == 1.0f)     sum -= lsp * omp * omp;
        else if (t < 1.0f) sum -= lsn * p * p * nw;

        // 3x3 NMS on logits, clamped indices (duplicates don't change max)
        const int sp = i & (HW_ - 1);
        const int y = sp >> 7, xq = sp & 127;
        const float* plane = Lb + (i - sp);
        const int ym = (y > 0) ? y - 1 : 0,   yp = (y < 127) ? y + 1 : 127;
        const int xm = (xq > 0) ? xq - 1 : 0, xp = (xq < 127) ? xq + 1 : 127;
        const float* r0 = plane + ym * 128;
        const float* r1 = plane + y  * 128;
        const float* r2 = plane + yp * 128;
        float m = fmaxf(fmaxf(fmaxf(r0[xm], r0[xq]), fmaxf(r0[xp], r1[xm])),
                 fmaxf(fmaxf(x, r1[xp]),
                 fmaxf(fmaxf(r2[xm], r2[xq]), r2[xp])));
        const float em   = expf(-fabsf(m));
        const float invm = 1.f / (1.f + em);
        const float pm   = (m >= 0.f) ? invm : em * invm;   // sigmoid(m), same path as p
        const unsigned key = (__float_as_uint(p) == __float_as_uint(pm)) ? __float_as_uint(p) : 0u;
        kb[i] = key;
        if (key) atomicAdd(&h[key >> 21], 1u);
    }

    #pragma unroll
    for (int off = 32; off > 0; off >>= 1) sum += __shfl_down(sum, off, 64);
    __shared__ float wsum[4];
    int lane = threadIdx.x & 63, wid = threadIdx.x >> 6;
    if (lane == 0) wsum[wid] = sum;
    __syncthreads();
    if (threadIdx.x == 0)
        atomicAdd(loss_out, wsum[0] + wsum[1] + wsum[2] + wsum[3]);

    unsigned* gh = hist + b * 2048;
    for (int j = threadIdx.x; j < 2048; j += 256) if (h[j]) atomicAdd(&gh[j], h[j]);
}

// ---------------------------------------------------------------------------
__global__ void hist2_k(const unsigned* __restrict__ keys, const unsigned* __restrict__ bin1,
                        unsigned* __restrict__ hist)
{
    __shared__ unsigned h[2048];
    for (int j = threadIdx.x; j < 2048; j += blockDim.x) h[j] = 0;
    __syncthreads();
    const int per_b = NCLS_ * HW_;
    const int b = blockIdx.y;
    const unsigned b1 = bin1[b];
    const unsigned* kb = keys + (size_t)b * per_b;
    for (int i = blockIdx.x * blockDim.x + threadIdx.x; i < per_b; i += gridDim.x * blockDim.x) {
        unsigned k = kb[i];
        if (k && (k >> 21) == b1) atomicAdd(&h[(k >> 10) & 2047], 1u);
    }
    __syncthreads();
    unsigned* gh = hist + b * 2048;
    for (int j = threadIdx.x; j < 2048; j += blockDim.x) if (h[j]) atomicAdd(&gh[j], h[j]);
}

__global__ void hist3_k(const unsigned* __restrict__ keys, const unsigned* __restrict__ pfx2,
                        unsigned* __restrict__ hist)
{
    __shared__ unsigned h[1024];
    for (int j = threadIdx.x; j < 1024; j += blockDim.x) h[j] = 0;
    __syncthreads();
    const int per_b = NCLS_ * HW_;
    const int b = blockIdx.y;
    const unsigned p2 = pfx2[b];
    const unsigned* kb = keys + (size_t)b * per_b;
    for (int i = blockIdx.x * blockDim.x + threadIdx.x; i < per_b; i += gridDim.x * blockDim.x) {
        unsigned k = kb[i];
        if (k && (k >> 10) == p2) atomicAdd(&h[k & 1023], 1u);
    }
    __syncthreads();
    unsigned* gh = hist + b * 1024;
    for (int j = threadIdx.x; j < 1024; j += blockDim.x) if (h[j]) atomicAdd(&gh[j], h[j]);
}

// ---------------------------------------------------------------------------
template<int NBINS, int LEVEL>
__global__ __launch_bounds__(256) void scan_k(
    const unsigned* __restrict__ hist,
    const unsigned* __restrict__ inPfx, const unsigned* __restrict__ inGt,
    unsigned* __restrict__ outPfx, unsigned* __restrict__ outGt)
{
    constexpr int PER = NBINS / 256;
    const int b = blockIdx.x;
    const int t = threadIdx.x;
    const unsigned* h = hist + b * NBINS;
    const unsigned base = (LEVEL == 1) ? 0u : inGt[b];

    unsigned v[PER];
    unsigned local = 0;
    #pragma unroll
    for (int i = 0; i < PER; i++) { v[i] = h[t * PER + i]; local += v[i]; }

    __shared__ unsigned ps[256];
    ps[t] = local;
    __syncthreads();
    #pragma unroll
    for (int off = 1; off < 256; off <<= 1) {
        unsigned add = (t + off < 256) ? ps[t + off] : 0u;
        __syncthreads();
        ps[t] += add;
        __syncthreads();
    }
    const unsigned sumAbove = (t == 255) ? 0u : ps[t + 1];

    unsigned sfx = sumAbove;
    #pragma unroll
    for (int i = PER - 1; i >= 0; i--) {
        unsigned sfx_next = sfx;
        sfx += v[i];
        bool cond     = (base + sfx      >= KTOP);
        bool condNext = (base + sfx_next >= KTOP);
        if (cond && !condNext) {
            unsigned sel = (unsigned)(t * PER + i);
            unsigned pfx = (LEVEL == 1) ? sel
                         : (LEVEL == 2) ? ((inPfx[b] << 11) | sel)
                                        : ((inPfx[b] << 10) | sel);
            outPfx[b] = pfx;
            outGt[b]  = base + sfx_next;
        }
    }
    if (t == 0 && base + ps[0] < KTOP) {
        unsigned pfx = (LEVEL == 1) ? 0u
                     : (LEVEL == 2) ? (inPfx[b] << 11)
                                    : (inPfx[b] << 10);
        outPfx[b] = pfx;
        outGt[b]  = base + ps[0];
    }
}

// ---------------------------------------------------------------------------
__global__ void select_k(const unsigned* __restrict__ keys, const unsigned* __restrict__ Tk,
                         unsigned* cntA, unsigned* cntB,
                         uint2* __restrict__ listA, unsigned* __restrict__ listB)
{
    const int per_b = NCLS_ * HW_;
    const int b = blockIdx.y;
    const unsigned T = Tk[b];
    const unsigned* kb = keys + (size_t)b * per_b;
    for (int i = blockIdx.x * blockDim.x + threadIdx.x; i < per_b; i += gridDim.x * blockDim.x) {
        unsigned k = kb[i];
        if (k > T) {
            unsigned pos = atomicAdd(&cntA[b], 1u);
            if (pos < KTOP) listA[b * KTOP + pos] = make_uint2(k, (unsigned)i);
        } else if (k == T && k != 0u) {
            unsigned pos = atomicAdd(&cntB[b], 1u);
            if (pos < CAPB) listB[b * CAPB + pos] = (unsigned)i;
        }
    }
}

// ---------------------------------------------------------------------------
__global__ void finalize_k(const unsigned* __restrict__ cntA, const unsigned* __restrict__ cntB,
                           const uint2* __restrict__ listA, const unsigned* __restrict__ listB,
                           const unsigned* __restrict__ Tk,
                           const float* __restrict__ wh, const float* __restrict__ off,
                           float* __restrict__ out)
{
    __shared__ unsigned sk[KTOP], si[KTOP], ok[KTOP], oi[KTOP];
    const int b = blockIdx.x;
    const int nA = (int)min(cntA[b], (unsigned)KTOP);
    const unsigned T = Tk[b];

    if ((int)threadIdx.x < nA) {
        uint2 e = listA[b * KTOP + threadIdx.x];
        sk[threadIdx.x] = e.x;
        si[threadIdx.x] = e.y;
    }
    __syncthreads();

    if (threadIdx.x == 0) {
        int need = KTOP - nA;
        unsigned nB = min(cntB[b], (unsigned)CAPB);
        long long prev = -1;
        for (int r = 0; r < need; r++) {
            unsigned best = 0xFFFFFFFFu;
            for (unsigned j = 0; j < nB; j++) {
                unsigned idx = listB[b * CAPB + j];
                if ((long long)idx > prev && idx < best) best = idx;
            }
            if (best == 0xFFFFFFFFu) { sk[nA + r] = 0u; si[nA + r] = 0u; }
            else { sk[nA + r] = T; si[nA + r] = best; prev = (long long)best; }
        }
    }
    __syncthreads();

    if (threadIdx.x < KTOP) {
        unsigned kk = sk[threadIdx.x], ii = si[threadIdx.x];
        int rank = 0;
        for (int j = 0; j < KTOP; j++) {
            unsigned kj = sk[j], ij = si[j];
            rank += (kj > kk) || (kj == kk && ij < ii);
        }
        ok[rank] = kk; oi[rank] = ii;
    }
    __syncthreads();

    if (threadIdx.x < KTOP) {
        int r = threadIdx.x;
        unsigned ind = oi[r];
        float score = __uint_as_float(ok[r]);
        int cls = (int)(ind / HW_);
        int sp  = (int)(ind % HW_);
        float ysf = (float)(sp >> 7);
        float xsf = (float)(sp & 127);
        float w0 = wh[((size_t)b * 2 + 0) * HW_ + sp];
        float h0 = wh[((size_t)b * 2 + 1) * HW_ + sp];
        float o0 = off[((size_t)b * 2 + 0) * HW_ + sp];
        float o1 = off[((size_t)b * 2 + 1) * HW_ + sp];
        float cx = xsf + o0;
        float cy = ysf + o1;
        float* boxes  = out;
        float* scores = out + (size_t)B_ * KTOP * 4;
        float* clses  = out + (size_t)B_ * KTOP * 5;
        boxes[((size_t)b * KTOP + r) * 4 + 0] = cx - w0 * 0.5f;
        boxes[((size_t)b * KTOP + r) * 4 + 1] = cy - h0 * 0.5f;
        boxes[((size_t)b * KTOP + r) * 4 + 2] = cx + w0 * 0.5f;
        boxes[((size_t)b * KTOP + r) * 4 + 3] = cy + h0 * 0.5f;
        scores[b * KTOP + r] = score;
        clses[b * KTOP + r]  = (float)cls;
    }
}

// ---------------------------------------------------------------------------
extern "C" void kernel_launch(void* const* d_in, const int* in_sizes, int n_in,
                              void* d_out, int out_size, void* d_ws, size_t ws_size,
                              hipStream_t stream)
{
    const float* feature      = (const float*)d_in[0];
    const float* targets      = (const float*)d_in[1];
    const float* cls_w        = (const float*)d_in[2];
    const float* cls_b        = (const float*)d_in[3];
    const float* bbox_w       = (const float*)d_in[4];
    const float* bbox_b       = (const float*)d_in[5];
    const float* off_w        = (const float*)d_in[6];
    const float* off_b        = (const float*)d_in[7];
    const float* cls_score_w  = (const float*)d_in[8];
    const float* cls_score_b  = (const float*)d_in[9];
    const float* bbox_pred_w  = (const float*)d_in[10];
    const float* bbox_pred_b  = (const float*)d_in[11];
    const float* center_off_w = (const float*)d_in[12];
    const float* center_off_b = (const float*)d_in[13];
    float* out = (float*)d_out;

    const size_t L_BYTES  = (size_t)B_ * NCLS_ * HW_ * 4;    // 21 MB
    const size_t P_BYTES  = (size_t)B_ * 2 * HW_ * 4;        // 0.5 MB
    const size_t WT_BYTES = (size_t)NIMG * WIMG_B;           // 4.1 MB

    char* ws = (char*)d_ws;
    const size_t lw = (size_t)C_ * C_ * 9;
    float* loss_ptr = out + (size_t)B_ * KTOP * 6;

    // layout: XA | XB(=Bf=keys) | L | WH | OFF | WT | sm   (~105 MB total)
    char* XA = ws;
    char* XB = ws + XSZ;
    float* L   = (float*)(ws + 2 * XSZ);
    float* WH  = (float*)(ws + 2 * XSZ + L_BYTES);
    float* OFF = (float*)(ws + 2 * XSZ + L_BYTES + P_BYTES);
    unsigned short* WT = (unsigned short*)(ws + 2 * XSZ + L_BYTES + 2 * P_BYTES);
    unsigned* sm = (unsigned*)(ws + 2 * XSZ + L_BYTES + 2 * P_BYTES + WT_BYTES);
    float* Bf = (float*)XB;
    unsigned* keys = (unsigned*)XB;

    unsigned* hist1 = sm;
    unsigned* hist2 = sm + 4 * 2048;
    unsigned* hist3 = sm + 8 * 2048;
    unsigned* bin1  = sm + 8 * 2048 + 4 * 1024;
    unsigned* gt1   = bin1 + 4;
    unsigned* pfx2  = bin1 + 8;
    unsigned* gt2   = bin1 + 12;
    unsigned* Tk    = bin1 + 16;
    unsigned* gt3   = bin1 + 20;
    unsigned* cntA  = bin1 + 24;
    unsigned* cntB  = bin1 + 28;
    uint2*    listA = (uint2*)(bin1 + 32);
    unsigned* listB = (unsigned*)(bin1 + 32 + 2 * B_ * KTOP);

    WtArgs wa;
    wa.src[0] = cls_w;        wa.cout[0] = 128;
    wa.src[1] = bbox_w;       wa.cout[1] = 128;
    wa.src[2] = off_w;        wa.cout[2] = 128;
    wa.src[3] = cls_w + lw;   wa.cout[3] = 128;
    wa.src[4] = bbox_w + lw;  wa.cout[4] = 128;
    wa.src[5] = off_w + lw;   wa.cout[5] = 128;
    wa.src[6] = cls_score_w;  wa.cout[6] = NCLS_;

    init_k<<<145, 256, 0, stream>>>(XA, XB, sm, loss_ptr);
    wtx_k<<<dim3(72, 1, NIMG), 256, 0, stream>>>(wa, WT);

    #define WIMG(i) (WT + (size_t)(i) * (WIMG_B / 2))

    // cls tower -> logits L
    conv_f_k<1, 1><<<512, 256, 0, stream>>>(feature, WIMG(0), cls_b,       nullptr, XA, 128);
    conv_x_k<1, 1><<<512, 256, 0, stream>>>(XA,      WIMG(3), cls_b + C_,  nullptr, XB, 128);
    conv_x_k<0, 0><<<512, 256, 0, stream>>>(XB,      WIMG(6), cls_score_b, L, nullptr, NCLS_);
    // bbox tower -> WH
    conv_f_k<1, 1><<<512, 256, 0, stream>>>(feature, WIMG(1), bbox_b,      nullptr, XA, 128);
    conv_x_k<1, 0><<<512, 256, 0, stream>>>(XA,      WIMG(4), bbox_b + C_, Bf, nullptr, 128);
    conv2out_k<<<dim3(64, 4), 256, 0, stream>>>(Bf, bbox_pred_w, bbox_pred_b, WH);
    // off tower -> OFF
    conv_f_k<1, 1><<<512, 256, 0, stream>>>(feature, WIMG(2), off_b,       nullptr, XA, 128);
    conv_x_k<1, 0><<<512, 256, 0, stream>>>(XA,      WIMG(5), off_b + C_,  Bf, nullptr, 128);
    conv2out_k<<<dim3(64, 4), 256, 0, stream>>>(Bf, center_off_w, center_off_b, OFF);

    lnh_k<<<dim3(512, B_), 256, 0, stream>>>(L, targets, loss_ptr, keys, hist1);

    dim3 hgrid(512, B_);
    scan_k<2048, 1><<<B_, 256, 0, stream>>>(hist1, nullptr, nullptr, bin1, gt1);
    hist2_k<<<hgrid, 256, 0, stream>>>(keys, bin1, hist2);
    scan_k<2048, 2><<<B_, 256, 0, stream>>>(hist2, bin1, gt1, pfx2, gt2);
    hist3_k<<<hgrid, 256, 0, stream>>>(keys, pfx2, hist3);
    scan_k<1024, 3><<<B_, 256, 0, stream>>>(hist3, pfx2, gt2, Tk, gt3);
    select_k<<<hgrid, 256, 0, stream>>>(keys, Tk, cntA, cntB, listA, listB);

    finalize_k<<<B_, 128, 0, stream>>>(cntA, cntB, listA, listB, Tk, WH, OFF, out);
}

// Round 8
// 548.054 us; speedup vs baseline: 2.8058x; 1.0535x over previous
//
#include <hip/hip_runtime.h>
#include <hip/hip_bf16.h>
#include <math.h>

#define B_    4
#define C_    128
#define H_    128
#define W_    128
#define HW_   (H_*W_)
#define NCLS_ 80
#define KTOP  100
#define CAPB  2048

typedef __attribute__((ext_vector_type(8)))  short bf16x8;
typedef __attribute__((ext_vector_type(16))) float f32x16;

// W image (register-load layout): per conv 36 stages of 16KB:
//   stage s = chunk*9+tap : [g 4][ks 2][part 2][32 couts x 32B]
//   lane l reads 16B at ((l&31)*32 + (l>>5)*16) -> row l31, k-half kh
#define WSTG_B     16384
#define WIMG_B     589824           // 36*16384
#define NIMG       7
// X'' image: [b*4+chunk] x [row 0..129] x [col 0..129] x 144B
#define XROWB      144
#define XCOLS      130
#define XPITCH     (XCOLS * XROWB)              // 18720
#define XSZ        ((size_t)16 * 130 * XPITCH)  // 38,937,600 per buffer
#define XLDS_B     25920                        // one X tile: 180 pos * 144B
#define LDS_TOT    (2 * XLDS_B)                 // 51840 (double-buffered X)
#define ZERO_N     20512                        // hists + scalars

__device__ __forceinline__ unsigned bf16_rne(float x) {
    unsigned u = __float_as_uint(x);
    return (u + 0x7FFFu + ((u >> 16) & 1u)) >> 16;
}
__device__ __forceinline__ void split2(float v0, float v1, unsigned& hiP, unsigned& loP) {
    unsigned h0 = bf16_rne(v0), h1 = bf16_rne(v1);
    float r0 = v0 - __uint_as_float(h0 << 16);
    float r1 = v1 - __uint_as_float(h1 << 16);
    unsigned l0 = bf16_rne(r0), l1 = bf16_rne(r1);
    hiP = h0 | (h1 << 16);
    loP = l0 | (l1 << 16);
}

#define MFMA32(a, bvec, c) __builtin_amdgcn_mfma_f32_32x32x16_bf16(a, bvec, c, 0, 0, 0)

// ---------------------------------------------------------------------------
// init: X'' borders for nbuf buffers (stride XSZ) + small scratch + loss slot
// ---------------------------------------------------------------------------
__global__ __launch_bounds__(256) void init_k(char* __restrict__ xbase, int nbuf,
                                              unsigned* __restrict__ sm, float* __restrict__ loss)
{
    const int i = blockIdx.x * 256 + threadIdx.x;
    const int nb = nbuf * 8256;
    if (i < nb) {
        char* buf = xbase + (size_t)(i / 8256) * XSZ;
        const int j = i % 8256;
        int R, col;
        if (j < 4160) {
            const int g = j / 260, rr = j % 260;
            R = g * 130 + ((rr < 130) ? 0 : 129);
            col = rr % 130;
        } else {
            const int q = j - 4160;
            const int g = q / 256, m = q % 256;
            R = g * 130 + 1 + (m >> 1);
            col = (m & 1) ? 129 : 0;
        }
        char* p = buf + ((size_t)R * XCOLS + col) * XROWB;
        #pragma unroll
        for (int k = 0; k < 9; k++) *(uint4*)(p + k * 16) = make_uint4(0, 0, 0, 0);
    } else {
        const int k = i - nb;
        if (k < ZERO_N) sm[k] = 0u;
        if (k == ZERO_N) *loss = 0.f;
    }
}

// ---------------------------------------------------------------------------
// Weight transform into the register-load layout.
// Images: 0=clsL1 1=bboxL1 2=offL1 3=clsL2 4=bboxL2 5=offL2 6=score
// ---------------------------------------------------------------------------
struct WtArgs { const float* src[NIMG]; int cout[NIMG]; };

__global__ __launch_bounds__(256) void wtx_k(WtArgs a, unsigned short* wt)
{
    const int img = blockIdx.z;
    const int idx = blockIdx.x * 256 + threadIdx.x;   // < 18432
    const int h  = idx & 1;
    const int ks = (idx >> 1) & 1;
    const int r  = (idx >> 2) & 31;
    const int g  = (idx >> 7) & 3;
    const int st = idx >> 9;
    if (st >= 36) return;
    const int tap = st % 9, chunk = st / 9;
    const float* w = a.src[img];
    const int Cout = a.cout[img];
    const int cout = g * 32 + r;
    const int cin0 = chunk * 32 + ks * 16 + h * 8;
    float v[8];
    #pragma unroll
    for (int j = 0; j < 8; j++)
        v[j] = (cout < Cout) ? w[((size_t)cout * 128 + cin0 + j) * 9 + tap] : 0.f;
    unsigned hiW[4], loW[4];
    #pragma unroll
    for (int j = 0; j < 4; j++) split2(v[2 * j], v[2 * j + 1], hiW[j], loW[j]);
    char* dst = (char*)wt + (size_t)img * WIMG_B + (size_t)st * WSTG_B
              + g * 4096 + ks * 2048 + r * 32 + h * 16;
    *(uint4*)dst          = make_uint4(hiW[0], hiW[1], hiW[2], hiW[3]);
    *(uint4*)(dst + 1024) = make_uint4(loW[0], loW[1], loW[2], loW[3]);
}

// ---------------------------------------------------------------------------
// Shared epilogue: write fp32 (XOUT=0) or X'' hi/lo (XOUT=1)
// ---------------------------------------------------------------------------
template<int RELU, int XOUT>
__device__ __forceinline__ void conv_epilogue(
    f32x16 (&acc)[2][2], const bool* act,
    const float* bias, float* outf, char* outx, int Cout,
    int b, int x0, int y0, int wm, int wn, int kh, int l31)
{
    #pragma unroll
    for (int f = 0; f < 2; f++) {
        if (!act[f]) continue;
        if (XOUT == 0) {
            #pragma unroll
            for (int r = 0; r < 16; r++) {
                const int co = wm * 64 + f * 32 + 4 * kh + (r & 3) + 8 * (r >> 2);
                if (co < Cout) {
                    const float bv = bias[co];
                    #pragma unroll
                    for (int fn = 0; fn < 2; fn++) {
                        const int p = wn * 64 + fn * 32 + l31;
                        float v = acc[f][fn][r] + bv;
                        if (RELU) v = fmaxf(v, 0.f);
                        outf[((size_t)b * Cout + co) * HW_ + (size_t)(y0 + (p >> 4)) * 128 + (x0 + (p & 15))] = v;
                    }
                }
            }
        } else {
            const int chunkO = wm * 2 + f;
            #pragma unroll
            for (int r2 = 0; r2 < 8; r2++) {
                const int r = 2 * r2;
                const int cij = 4 * kh + (r & 3) + 8 * (r >> 2);
                const int co0 = wm * 64 + f * 32 + cij;
                const float b0v = bias[co0], b1v = bias[co0 + 1];
                #pragma unroll
                for (int fn = 0; fn < 2; fn++) {
                    const int p = wn * 64 + fn * 32 + l31;
                    float v0 = acc[f][fn][r] + b0v;
                    float v1 = acc[f][fn][r + 1] + b1v;
                    if (RELU) { v0 = fmaxf(v0, 0.f); v1 = fmaxf(v1, 0.f); }
                    unsigned hiP, loP; split2(v0, v1, hiP, loP);
                    char* rowp = outx + ((size_t)((b * 4 + chunkO) * 130 + (y0 + (p >> 4) + 1)) * XCOLS
                                        + (x0 + (p & 15) + 1)) * XROWB;
                    *(unsigned*)(rowp + 2 * cij)      = hiP;
                    *(unsigned*)(rowp + 64 + 2 * cij) = loP;
                }
            }
        }
    }
}

// W prefetch: honest 2-slot rotation; slot = 8 bf16x8 (32 VGPR). All slot
// indices compile-time literals via chunk-unrolled macros (rule #20).
#define WLOAD_(SLOT, SIDX) do {                                               \
    const char* wp_ = wb + (size_t)(SIDX) * WSTG_B;                           \
    _Pragma("unroll")                                                         \
    for (int f_ = 0; f_ < 2; f_++) {                                          \
        _Pragma("unroll")                                                     \
        for (int k_ = 0; k_ < 2; k_++) {                                      \
            wf[SLOT][f_ * 2 + k_]     = *(const bf16x8*)(wp_ + f_ * 4096 + k_ * 2048);        \
            wf[SLOT][4 + f_ * 2 + k_] = *(const bf16x8*)(wp_ + f_ * 4096 + k_ * 2048 + 1024); \
        }                                                                     \
    }                                                                         \
} while (0)

#define MFMA_TAP_(CUR, DOFF) do {                                             \
    _Pragma("unroll")                                                         \
    for (int ks = 0; ks < 2; ks++) {                                          \
        bf16x8 bh[2], bl[2];                                                  \
        _Pragma("unroll")                                                     \
        for (int fn = 0; fn < 2; fn++) {                                      \
            bh[fn] = *(const bf16x8*)(lds + baddr[fn] + (DOFF) + ks * 32);      \
            bl[fn] = *(const bf16x8*)(lds + baddr[fn] + (DOFF) + ks * 32 + 64); \
        }                                                                     \
        _Pragma("unroll")                                                     \
        for (int f = 0; f < 2; f++) if (act[f]) {                             \
            _Pragma("unroll")                                                 \
            for (int fn = 0; fn < 2; fn++)                                    \
                acc[f][fn] = MFMA32(wf[CUR][f * 2 + ks], bh[fn], acc[f][fn]); \
        }                                                                     \
        _Pragma("unroll")                                                     \
        for (int f = 0; f < 2; f++) if (act[f]) {                             \
            _Pragma("unroll")                                                 \
            for (int fn = 0; fn < 2; fn++)                                    \
                acc[f][fn] = MFMA32(wf[CUR][f * 2 + ks], bl[fn], acc[f][fn]); \
        }                                                                     \
        _Pragma("unroll")                                                     \
        for (int f = 0; f < 2; f++) if (act[f]) {                             \
            _Pragma("unroll")                                                 \
            for (int fn = 0; fn < 2; fn++)                                    \
                acc[f][fn] = MFMA32(wf[CUR][4 + f * 2 + ks], bh[fn], acc[f][fn]); \
        }                                                                     \
    }                                                                         \
} while (0)

// Common body macros for the fp32-input conv (shared by single & fused forms)
#define CONVF_SETUP()                                                         \
    __shared__ __align__(16) char lds[LDS_TOT];                               \
    const int t    = threadIdx.x;                                             \
    const int lane = t & 63;                                                  \
    const int wv   = t >> 6;                                                  \
    const int wm   = wv >> 1;                                                 \
    const int wn   = wv & 1;                                                  \
    const int l31  = lane & 31;                                               \
    const int kh   = lane >> 5;                                               \
    const int bi = blockIdx.x;                                                \
    const int x0 = (bi & 7) << 4;                                             \
    const int y0 = ((bi >> 3) & 15) << 3;                                     \
    const int b  = bi >> 7;                                                   \
    int baddr[2];                                                             \
    _Pragma("unroll")                                                         \
    for (int fn = 0; fn < 2; fn++) {                                          \
        const int p = wn * 64 + fn * 32 + l31;                                \
        baddr[fn] = ((p >> 4) * 18 + (p & 15)) * 144 + kh * 16;               \
    }                                                                         \
    const int wlane = ((lane & 31) << 5) | (kh << 4);                         \
    f32x16 acc[2][2];                                                         \
    _Pragma("unroll")                                                         \
    for (int i_ = 0; i_ < 2; i_++)                                            \
        _Pragma("unroll")                                                     \
        for (int j_ = 0; j_ < 2; j_++)                                        \
            _Pragma("unroll")                                                 \
            for (int r_ = 0; r_ < 16; r_++) acc[i_][j_][r_] = 0.f;

#define LOADX_F(ch) do {                                                      \
    _Pragma("unroll")                                                         \
    for (int it = 0; it < 12; it++) {                                         \
        const int idx = t + it * 256;                                         \
        const int pl = idx & 15, cp = (idx >> 4) & 15, ph = idx >> 8;         \
        const int pos = ph * 16 + pl;                                         \
        float v0 = 0.f, v1 = 0.f;                                             \
        if (pos < 180) {                                                      \
            const int hy = pos / 18, hx = pos - hy * 18;                      \
            const int gy = y0 - 1 + hy, gx = x0 - 1 + hx;                     \
            if ((unsigned)gy < 128u && (unsigned)gx < 128u) {                 \
                const float* p0 = inb + (size_t)((ch) * 32 + 2 * cp) * HW_    \
                                      + gy * 128 + gx;                        \
                v0 = p0[0]; v1 = p0[HW_];                                     \
            }                                                                 \
        }                                                                     \
        xa[it] = v0; xb[it] = v1;                                             \
    }                                                                         \
} while (0)

#define STOREX_F(bufsel) do {                                                 \
    _Pragma("unroll")                                                         \
    for (int it = 0; it < 12; it++) {                                         \
        const int idx = t + it * 256;                                         \
        const int pl = idx & 15, cp = (idx >> 4) & 15, ph = idx >> 8;         \
        const int pos = ph * 16 + pl;                                         \
        if (pos < 180) {                                                      \
            unsigned hiP, loP; split2(xa[it], xb[it], hiP, loP);              \
            *(unsigned*)(lds + (bufsel) * XLDS_B + pos * 144 + 4 * cp)      = hiP; \
            *(unsigned*)(lds + (bufsel) * XLDS_B + pos * 144 + 64 + 4 * cp) = loP; \
        }                                                                     \
    }                                                                         \
} while (0)

#define TAPF_(CH, TAP, CUR, NXT) do {                                         \
    if ((CH) * 9 + (TAP) + 1 < 36) WLOAD_(NXT, (CH) * 9 + (TAP) + 1);         \
    MFMA_TAP_(CUR, (((TAP) / 3) * 18 + ((TAP) % 3)) * 144 + ((CH) & 1) * XLDS_B); \
} while (0)

#define CHUNKF_(CH, SA, SB) do {                                              \
    TAPF_(CH, 0, SA, SB); TAPF_(CH, 1, SB, SA); TAPF_(CH, 2, SA, SB);         \
    TAPF_(CH, 3, SB, SA); TAPF_(CH, 4, SA, SB); TAPF_(CH, 5, SB, SA);         \
    if ((CH) < 3) LOADX_F((CH) + 1);                                          \
    TAPF_(CH, 6, SA, SB); TAPF_(CH, 7, SB, SA); TAPF_(CH, 8, SA, SB);         \
    if ((CH) < 3) { STOREX_F(((CH) + 1) & 1); __syncthreads(); }              \
} while (0)

#define CONVF_MAIN()                                                          \
    bf16x8 wf[2][8];                                                          \
    WLOAD_(0, 0);                                                             \
    float xa[12], xb[12];                                                     \
    LOADX_F(0);                                                               \
    STOREX_F(0);                                                              \
    __syncthreads();                                                          \
    CHUNKF_(0, 0, 1);                                                         \
    CHUNKF_(1, 1, 0);                                                         \
    CHUNKF_(2, 0, 1);                                                         \
    CHUNKF_(3, 1, 0);

// ---------------------------------------------------------------------------
// MFMA conv, fp32 input (single-tower form, fallback path)
// ---------------------------------------------------------------------------
template<int RELU, int XOUT>
__global__ __launch_bounds__(256, 2) void conv_f_k(
    const float* __restrict__ in, const unsigned short* __restrict__ wt,
    const float* __restrict__ bias, float* __restrict__ outf,
    char* __restrict__ outx, int Cout)
{
    CONVF_SETUP();
    bool act[2];
    #pragma unroll
    for (int f = 0; f < 2; f++) act[f] = (wm * 64 + f * 32) < Cout;
    const char* wb = (const char*)wt + wm * 8192 + wlane;
    const float* inb = in + (size_t)b * 128 * HW_;
    CONVF_MAIN();
    conv_epilogue<RELU, XOUT>(acc, act, bias, outf, outx, Cout, b, x0, y0, wm, wn, kh, l31);
}

// ---------------------------------------------------------------------------
// Fused 3-tower fp32-input conv (stage 1): grid (512, 3). RELU=1, XOUT=1.
// ---------------------------------------------------------------------------
struct F3Args { const unsigned short* wt[3]; const float* bias[3]; char* outx[3]; };

__global__ __launch_bounds__(256, 2) void convF3_k(const float* __restrict__ in, F3Args a)
{
    const int ty = blockIdx.y;
    const unsigned short* wt = a.wt[ty];
    const float* bias = a.bias[ty];
    char* outx = a.outx[ty];

    CONVF_SETUP();
    bool act[2]; act[0] = true; act[1] = true;
    const char* wb = (const char*)wt + wm * 8192 + wlane;
    const float* inb = in + (size_t)b * 128 * HW_;
    CONVF_MAIN();
    conv_epilogue<1, 1>(acc, act, bias, nullptr, outx, 128, b, x0, y0, wm, wn, kh, l31);
}

// Common body macros for the X''-input conv
#define CONVX_SETUP()                                                         \
    __shared__ __align__(16) char lds[LDS_TOT];                               \
    const int t    = threadIdx.x;                                             \
    const int lane = t & 63;                                                  \
    const int wv   = t >> 6;                                                  \
    const int wm   = wv >> 1;                                                 \
    const int wn   = wv & 1;                                                  \
    const int l31  = lane & 31;                                               \
    const int kh   = lane >> 5;                                               \
    const int bi = blockIdx.x;                                                \
    const int x0 = (bi & 7) << 4;                                             \
    const int y0 = ((bi >> 3) & 15) << 3;                                     \
    const int b  = bi >> 7;                                                   \
    int baddr[2];                                                             \
    _Pragma("unroll")                                                         \
    for (int fn = 0; fn < 2; fn++) {                                          \
        const int p = wn * 64 + fn * 32 + l31;                                \
        baddr[fn] = (p >> 4) * 2592 + (p & 15) * 144 + kh * 16;               \
    }                                                                         \
    const int wlane = ((lane & 31) << 5) | (kh << 4);                         \
    f32x16 acc[2][2];                                                         \
    _Pragma("unroll")                                                         \
    for (int i_ = 0; i_ < 2; i_++)                                            \
        _Pragma("unroll")                                                     \
        for (int j_ = 0; j_ < 2; j_++)                                        \
            _Pragma("unroll")                                                 \
            for (int r_ = 0; r_ < 16; r_++) acc[i_][j_][r_] = 0.f;

#define CONVX_PROLOG()                                                        \
    {                                                                         \
        const size_t rowbase = ((size_t)((b * 4 + 0) * 130 + y0) * XCOLS + x0) * XROWB; \
        _Pragma("unroll")                                                     \
        for (int gg = 0; gg < 5; gg++) {                                      \
            const int g = wv * 5 + gg;                                        \
            const int hy = g >> 1, i = g & 1;                                 \
            __builtin_amdgcn_global_load_lds(                                 \
                (const __attribute__((address_space(1))) unsigned*)           \
                    (xin + rowbase + (size_t)hy * XPITCH + i * 1024 + lane * 16), \
                (__attribute__((address_space(3))) unsigned*)(lds + hy * 2592 + i * 1024), \
                16, 0, 0);                                                    \
        }                                                                     \
        for (int u = t; u < 340; u += 256) {                                  \
            const int hy = u / 34;                                            \
            const int off = 2048 + (u % 34) * 16;                             \
            uint4 v = *(const uint4*)(xin + rowbase + (size_t)hy * XPITCH + off); \
            *(uint4*)(lds + hy * 2592 + off) = v;                             \
        }                                                                     \
    }                                                                         \
    __syncthreads();

#define TAPX_(CH, TAP, CUR, NXT) do {                                         \
    if ((CH) * 9 + (TAP) + 1 < 36) WLOAD_(NXT, (CH) * 9 + (TAP) + 1);         \
    MFMA_TAP_(CUR, ((TAP) / 3) * 2592 + ((TAP) % 3) * 144 + ((CH) & 1) * XLDS_B); \
} while (0)

#define CHUNKX_(CH, SA, SB) do {                                              \
    uint4 tl0_, tl1_; bool h1_ = false;                                       \
    const int xd_ = (((CH) + 1) & 1) * XLDS_B;                                \
    if ((CH) < 3) {                                                           \
        const size_t rowb1_ = ((size_t)((b * 4 + (CH) + 1) * 130 + y0) * XCOLS + x0) * XROWB; \
        _Pragma("unroll")                                                     \
        for (int gg = 0; gg < 5; gg++) {                                      \
            const int g = wv * 5 + gg;                                        \
            const int hy = g >> 1, ii = g & 1;                                \
            __builtin_amdgcn_global_load_lds(                                 \
                (const __attribute__((address_space(1))) unsigned*)           \
                    (xin + rowb1_ + (size_t)hy * XPITCH + ii * 1024 + lane * 16), \
                (__attribute__((address_space(3))) unsigned*)(lds + xd_ + hy * 2592 + ii * 1024), \
                16, 0, 0);                                                    \
        }                                                                     \
        {                                                                     \
            const int hy = t / 34, off = 2048 + (t % 34) * 16;                \
            tl0_ = *(const uint4*)(xin + rowb1_ + (size_t)hy * XPITCH + off); \
        }                                                                     \
        h1_ = (t < 84);                                                       \
        if (h1_) {                                                            \
            const int u = t + 256;                                            \
            const int hy = u / 34, off = 2048 + (u % 34) * 16;                \
            tl1_ = *(const uint4*)(xin + rowb1_ + (size_t)hy * XPITCH + off); \
        }                                                                     \
    }                                                                         \
    TAPX_(CH, 0, SA, SB); TAPX_(CH, 1, SB, SA); TAPX_(CH, 2, SA, SB);         \
    TAPX_(CH, 3, SB, SA); TAPX_(CH, 4, SA, SB); TAPX_(CH, 5, SB, SA);         \
    TAPX_(CH, 6, SA, SB); TAPX_(CH, 7, SB, SA); TAPX_(CH, 8, SA, SB);         \
    if ((CH) < 3) {                                                           \
        {                                                                     \
            const int hy = t / 34, off = 2048 + (t % 34) * 16;                \
            *(uint4*)(lds + xd_ + hy * 2592 + off) = tl0_;                    \
        }                                                                     \
        if (h1_) {                                                            \
            const int u = t + 256;                                            \
            const int hy = u / 34, off = 2048 + (u % 34) * 16;                \
            *(uint4*)(lds + xd_ + hy * 2592 + off) = tl1_;                    \
        }                                                                     \
        __syncthreads();                                                      \
    }                                                                         \
} while (0)

#define CONVX_MAIN()                                                          \
    bf16x8 wf[2][8];                                                          \
    WLOAD_(0, 0);                                                             \
    CONVX_PROLOG();                                                           \
    CHUNKX_(0, 0, 1);                                                         \
    CHUNKX_(1, 1, 0);                                                         \
    CHUNKX_(2, 0, 1);                                                         \
    CHUNKX_(3, 1, 0);

// ---------------------------------------------------------------------------
// MFMA conv, X'' input (single-tower form, fallback + score conv)
// ---------------------------------------------------------------------------
template<int RELU, int XOUT>
__global__ __launch_bounds__(256, 2) void conv_x_k(
    const char* __restrict__ xin, const unsigned short* __restrict__ wt,
    const float* __restrict__ bias, float* __restrict__ outf,
    char* __restrict__ outx, int Cout)
{
    CONVX_SETUP();
    bool act[2];
    #pragma unroll
    for (int f = 0; f < 2; f++) act[f] = (wm * 64 + f * 32) < Cout;
    const char* wb = (const char*)wt + wm * 8192 + wlane;
    CONVX_MAIN();
    conv_epilogue<RELU, XOUT>(acc, act, bias, outf, outx, Cout, b, x0, y0, wm, wn, kh, l31);
}

// ---------------------------------------------------------------------------
// Fused 3-tower X''-input conv (stage 2): grid (512, 3). RELU=1, runtime xout.
// ---------------------------------------------------------------------------
struct X3Args {
    const char* xin[3]; const unsigned short* wt[3]; const float* bias[3];
    float* outf[3]; char* outx[3]; int xout[3];
};

__global__ __launch_bounds__(256, 2) void convX3_k(X3Args a)
{
    const int ty = blockIdx.y;
    const char* xin = a.xin[ty];
    const unsigned short* wt = a.wt[ty];
    const float* bias = a.bias[ty];
    float* outf = a.outf[ty];
    char* outx = a.outx[ty];
    const int xo = a.xout[ty];

    CONVX_SETUP();
    bool act[2]; act[0] = true; act[1] = true;
    const char* wb = (const char*)wt + wm * 8192 + wlane;
    CONVX_MAIN();
    if (xo) conv_epilogue<1, 1>(acc, act, bias, nullptr, outx, 128, b, x0, y0, wm, wn, kh, l31);
    else    conv_epilogue<1, 0>(acc, act, bias, outf, nullptr, 128, b, x0, y0, wm, wn, kh, l31);
}

// ---------------------------------------------------------------------------
// Direct conv for Cout=2 heads (fp32 input), single head (fallback)
// ---------------------------------------------------------------------------
__device__ __forceinline__ void conv2out_body(
    const float* in, const float* w, const float* bias, float* out)
{
    __shared__ float ws[128 * 9 * 2];
    const int t = threadIdx.x;
    for (int i = t; i < 2304; i += 256) {
        const int co = i & 1, tap = (i >> 1) % 9, ci = i / 18;
        ws[i] = w[(size_t)co * 1152 + ci * 9 + tap];
    }
    __syncthreads();

    const int b  = blockIdx.y;
    const int y  = (blockIdx.x >> 3) * 16 + (t >> 4);
    const int x  = (blockIdx.x & 7) * 16 + (t & 15);
    const float* inb = in + (size_t)b * 128 * HW_ + y * 128 + x;

    float a0 = bias[0], a1 = bias[1];
    #pragma unroll 2
    for (int ci = 0; ci < 128; ci++) {
        const float* p  = inb + (size_t)ci * HW_;
        const float* wp = ws + ci * 18;
        #pragma unroll
        for (int tap = 0; tap < 9; tap++) {
            const int dy = tap / 3 - 1, dx = tap % 3 - 1;
            const int yy = y + dy, xx = x + dx;
            float v = 0.f;
            if ((unsigned)yy < 128u && (unsigned)xx < 128u) v = p[dy * 128 + dx];
            a0 = fmaf(v, wp[tap * 2 + 0], a0);
            a1 = fmaf(v, wp[tap * 2 + 1], a1);
        }
    }
    out[((size_t)b * 2 + 0) * HW_ + y * 128 + x] = a0;
    out[((size_t)b * 2 + 1) * HW_ + y * 128 + x] = a1;
}

__global__ __launch_bounds__(256) void conv2out_k(
    const float* __restrict__ in, const float* __restrict__ w,
    const float* __restrict__ bias, float* __restrict__ out)
{
    conv2out_body(in, w, bias, out);
}

// Fused 2-head variant (z selects head) for the fused path
__global__ __launch_bounds__(256) void conv2out2_k(
    const float* in0, const float* in1,
    const float* w0, const float* w1,
    const float* b0, const float* b1,
    float* out0, float* out1)
{
    const int z = blockIdx.z;
    conv2out_body(z ? in1 : in0, z ? w1 : w0, z ? b1 : b0, z ? out1 : out0);
}

// ---------------------------------------------------------------------------
// Fused: focal loss + 3x3 NMS (clamped-index max on logits) + hist1.
// ---------------------------------------------------------------------------
__global__ __launch_bounds__(256) void lnh_k(
    const float* __restrict__ L, const float* __restrict__ targets,
    float* __restrict__ loss_out, unsigned* __restrict__ keys,
    unsigned* __restrict__ hist)
{
    __shared__ unsigned h[2048];
    for (int j = threadIdx.x; j < 2048; j += 256) h[j] = 0;
    __syncthreads();

    const int per_b = NCLS_ * HW_;
    const int b = blockIdx.y;
    const float* Lb = L + (size_t)b * per_b;
    const float* Tb = targets + (size_t)b * per_b;
    unsigned* kb = keys + (size_t)b * per_b;

    float sum = 0.f;
    for (int i = blockIdx.x * 256 + threadIdx.x; i < per_b; i += gridDim.x * 256) {
        const float x = Lb[i];
        const float t = Tb[i];
        const float e   = expf(-fabsf(x));
        const float inv = 1.f / (1.f + e);
        const float lp  = log1pf(e);
        const bool  xe  = (x >= 0.f);
        const float p   = xe ? inv : e * inv;       // sigmoid(x)
        const float lsp = xe ? -lp : (x - lp);      // log sigmoid(x)
        const float lsn = lsp - x;                  // log sigmoid(-x)
        float om = 1.f - t;
        float nw = om * om; nw *= nw;
        const float omp = 1.f - p;
        if (t == 1.0f)     sum -= lsp * omp * omp;
        else if (t < 1.0f) sum -= lsn * p * p * nw;

        // 3x3 NMS on logits, clamped indices (duplicates don't change max)
        const int sp = i & (HW_ - 1);
        const int y = sp >> 7, xq = sp & 127;
        const float* plane = Lb + (i - sp);
        const int ym = (y > 0) ? y - 1 : 0,   yp = (y < 127) ? y + 1 : 127;
        const int xm = (xq > 0) ? xq - 1 : 0, xp = (xq < 127) ? xq + 1 : 127;
        const float* r0 = plane + ym * 128;
        const float* r1 = plane + y  * 128;
        const float* r2 = plane + yp * 128;
        float m = fmaxf(fmaxf(fmaxf(r0[xm], r0[xq]), fmaxf(r0[xp], r1[xm])),
                 fmaxf(fmaxf(x, r1[xp]),
                 fmaxf(fmaxf(r2[xm], r2[xq]), r2[xp])));
        const float em   = expf(-fabsf(m));
        const float invm = 1.f / (1.f + em);
        const float pm   = (m >= 0.f) ? invm : em * invm;   // sigmoid(m), same path as p
        const unsigned key = (__float_as_uint(p) == __float_as_uint(pm)) ? __float_as_uint(p) : 0u;
        kb[i] = key;
        if (key) atomicAdd(&h[key >> 21], 1u);
    }

    #pragma unroll
    for (int off = 32; off > 0; off >>= 1) sum += __shfl_down(sum, off, 64);
    __shared__ float wsum[4];
    int lane = threadIdx.x & 63, wid = threadIdx.x >> 6;
    if (lane == 0) wsum[wid] = sum;
    __syncthreads();
    if (threadIdx.x == 0)
        atomicAdd(loss_out, wsum[0] + wsum[1] + wsum[2] + wsum[3]);

    unsigned* gh = hist + b * 2048;
    for (int j = threadIdx.x; j < 2048; j += 256) if (h[j]) atomicAdd(&gh[j], h[j]);
}

// ---------------------------------------------------------------------------
__global__ void hist2_k(const unsigned* __restrict__ keys, const unsigned* __restrict__ bin1,
                        unsigned* __restrict__ hist)
{
    __shared__ unsigned h[2048];
    for (int j = threadIdx.x; j < 2048; j += blockDim.x) h[j] = 0;
    __syncthreads();
    const int per_b = NCLS_ * HW_;
    const int b = blockIdx.y;
    const unsigned b1 = bin1[b];
    const unsigned* kb = keys + (size_t)b * per_b;
    for (int i = blockIdx.x * blockDim.x + threadIdx.x; i < per_b; i += gridDim.x * blockDim.x) {
        unsigned k = kb[i];
        if (k && (k >> 21) == b1) atomicAdd(&h[(k >> 10) & 2047], 1u);
    }
    __syncthreads();
    unsigned* gh = hist + b * 2048;
    for (int j = threadIdx.x; j < 2048; j += blockDim.x) if (h[j]) atomicAdd(&gh[j], h[j]);
}

__global__ void hist3_k(const unsigned* __restrict__ keys, const unsigned* __restrict__ pfx2,
                        unsigned* __restrict__ hist)
{
    __shared__ unsigned h[1024];
    for (int j = threadIdx.x; j < 1024; j += blockDim.x) h[j] = 0;
    __syncthreads();
    const int per_b = NCLS_ * HW_;
    const int b = blockIdx.y;
    const unsigned p2 = pfx2[b];
    const unsigned* kb = keys + (size_t)b * per_b;
    for (int i = blockIdx.x * blockDim.x + threadIdx.x; i < per_b; i += gridDim.x * blockDim.x) {
        unsigned k = kb[i];
        if (k && (k >> 10) == p2) atomicAdd(&h[k & 1023], 1u);
    }
    __syncthreads();
    unsigned* gh = hist + b * 1024;
    for (int j = threadIdx.x; j < 1024; j += blockDim.x) if (h[j]) atomicAdd(&gh[j], h[j]);
}

// ---------------------------------------------------------------------------
template<int NBINS, int LEVEL>
__global__ __launch_bounds__(256) void scan_k(
    const unsigned* __restrict__ hist,
    const unsigned* __restrict__ inPfx, const unsigned* __restrict__ inGt,
    unsigned* __restrict__ outPfx, unsigned* __restrict__ outGt)
{
    constexpr int PER = NBINS / 256;
    const int b = blockIdx.x;
    const int t = threadIdx.x;
    const unsigned* h = hist + b * NBINS;
    const unsigned base = (LEVEL == 1) ? 0u : inGt[b];

    unsigned v[PER];
    unsigned local = 0;
    #pragma unroll
    for (int i = 0; i < PER; i++) { v[i] = h[t * PER + i]; local += v[i]; }

    __shared__ unsigned ps[256];
    ps[t] = local;
    __syncthreads();
    #pragma unroll
    for (int off = 1; off < 256; off <<= 1) {
        unsigned add = (t + off < 256) ? ps[t + off] : 0u;
        __syncthreads();
        ps[t] += add;
        __syncthreads();
    }
    const unsigned sumAbove = (t == 255) ? 0u : ps[t + 1];

    unsigned sfx = sumAbove;
    #pragma unroll
    for (int i = PER - 1; i >= 0; i--) {
        unsigned sfx_next = sfx;
        sfx += v[i];
        bool cond     = (base + sfx      >= KTOP);
        bool condNext = (base + sfx_next >= KTOP);
        if (cond && !condNext) {
            unsigned sel = (unsigned)(t * PER + i);
            unsigned pfx = (LEVEL == 1) ? sel
                         : (LEVEL == 2) ? ((inPfx[b] << 11) | sel)
                                        : ((inPfx[b] << 10) | sel);
            outPfx[b] = pfx;
            outGt[b]  = base + sfx_next;
        }
    }
    if (t == 0 && base + ps[0] < KTOP) {
        unsigned pfx = (LEVEL == 1) ? 0u
                     : (LEVEL == 2) ? (inPfx[b] << 11)
                                    : (inPfx[b] << 10);
        outPfx[b] = pfx;
        outGt[b]  = base + ps[0];
    }
}

// ---------------------------------------------------------------------------
__global__ void select_k(const unsigned* __restrict__ keys, const unsigned* __restrict__ Tk,
                         unsigned* cntA, unsigned* cntB,
                         uint2* __restrict__ listA, unsigned* __restrict__ listB)
{
    const int per_b = NCLS_ * HW_;
    const int b = blockIdx.y;
    const unsigned T = Tk[b];
    const unsigned* kb = keys + (size_t)b * per_b;
    for (int i = blockIdx.x * blockDim.x + threadIdx.x; i < per_b; i += gridDim.x * blockDim.x) {
        unsigned k = kb[i];
        if (k > T) {
            unsigned pos = atomicAdd(&cntA[b], 1u);
            if (pos < KTOP) listA[b * KTOP + pos] = make_uint2(k, (unsigned)i);
        } else if (k == T && k != 0u) {
            unsigned pos = atomicAdd(&cntB[b], 1u);
            if (pos < CAPB) listB[b * CAPB + pos] = (unsigned)i;
        }
    }
}

// ---------------------------------------------------------------------------
__global__ void finalize_k(const unsigned* __restrict__ cntA, const unsigned* __restrict__ cntB,
                           const uint2* __restrict__ listA, const unsigned* __restrict__ listB,
                           const unsigned* __restrict__ Tk,
                           const float* __restrict__ wh, const float* __restrict__ off,
                           float* __restrict__ out)
{
    __shared__ unsigned sk[KTOP], si[KTOP], ok[KTOP], oi[KTOP];
    const int b = blockIdx.x;
    const int nA = (int)min(cntA[b], (unsigned)KTOP);
    const unsigned T = Tk[b];

    if ((int)threadIdx.x < nA) {
        uint2 e = listA[b * KTOP + threadIdx.x];
        sk[threadIdx.x] = e.x;
        si[threadIdx.x] = e.y;
    }
    __syncthreads();

    if (threadIdx.x == 0) {
        int need = KTOP - nA;
        unsigned nB = min(cntB[b], (unsigned)CAPB);
        long long prev = -1;
        for (int r = 0; r < need; r++) {
            unsigned best = 0xFFFFFFFFu;
            for (unsigned j = 0; j < nB; j++) {
                unsigned idx = listB[b * CAPB + j];
                if ((long long)idx > prev && idx < best) best = idx;
            }
            if (best == 0xFFFFFFFFu) { sk[nA + r] = 0u; si[nA + r] = 0u; }
            else { sk[nA + r] = T; si[nA + r] = best; prev = (long long)best; }
        }
    }
    __syncthreads();

    if (threadIdx.x < KTOP) {
        unsigned kk = sk[threadIdx.x], ii = si[threadIdx.x];
        int rank = 0;
        for (int j = 0; j < KTOP; j++) {
            unsigned kj = sk[j], ij = si[j];
            rank += (kj > kk) || (kj == kk && ij < ii);
        }
        ok[rank] = kk; oi[rank] = ii;
    }
    __syncthreads();

    if (threadIdx.x < KTOP) {
        int r = threadIdx.x;
        unsigned ind = oi[r];
        float score = __uint_as_float(ok[r]);
        int cls = (int)(ind / HW_);
        int sp  = (int)(ind % HW_);
        float ysf = (float)(sp >> 7);
        float xsf = (float)(sp & 127);
        float w0 = wh[((size_t)b * 2 + 0) * HW_ + sp];
        float h0 = wh[((size_t)b * 2 + 1) * HW_ + sp];
        float o0 = off[((size_t)b * 2 + 0) * HW_ + sp];
        float o1 = off[((size_t)b * 2 + 1) * HW_ + sp];
        float cx = xsf + o0;
        float cy = ysf + o1;
        float* boxes  = out;
        float* scores = out + (size_t)B_ * KTOP * 4;
        float* clses  = out + (size_t)B_ * KTOP * 5;
        boxes[((size_t)b * KTOP + r) * 4 + 0] = cx - w0 * 0.5f;
        boxes[((size_t)b * KTOP + r) * 4 + 1] = cy - h0 * 0.5f;
        boxes[((size_t)b * KTOP + r) * 4 + 2] = cx + w0 * 0.5f;
        boxes[((size_t)b * KTOP + r) * 4 + 3] = cy + h0 * 0.5f;
        scores[b * KTOP + r] = score;
        clses[b * KTOP + r]  = (float)cls;
    }
}

// ---------------------------------------------------------------------------
extern "C" void kernel_launch(void* const* d_in, const int* in_sizes, int n_in,
                              void* d_out, int out_size, void* d_ws, size_t ws_size,
                              hipStream_t stream)
{
    const float* feature      = (const float*)d_in[0];
    const float* targets      = (const float*)d_in[1];
    const float* cls_w        = (const float*)d_in[2];
    const float* cls_b        = (const float*)d_in[3];
    const float* bbox_w       = (const float*)d_in[4];
    const float* bbox_b       = (const float*)d_in[5];
    const float* off_w        = (const float*)d_in[6];
    const float* off_b        = (const float*)d_in[7];
    const float* cls_score_w  = (const float*)d_in[8];
    const float* cls_score_b  = (const float*)d_in[9];
    const float* bbox_pred_w  = (const float*)d_in[10];
    const float* bbox_pred_b  = (const float*)d_in[11];
    const float* center_off_w = (const float*)d_in[12];
    const float* center_off_b = (const float*)d_in[13];
    float* out = (float*)d_out;

    const size_t L_BYTES  = (size_t)B_ * NCLS_ * HW_ * 4;    // 21 MB
    const size_t P_BYTES  = (size_t)B_ * 2 * HW_ * 4;        // 0.5 MB
    const size_t WT_BYTES = (size_t)NIMG * WIMG_B;           // 4.1 MB
    const size_t SM_BYTES = (size_t)1 << 18;                 // 256 KB scratch region

    char* ws = (char*)d_ws;
    const size_t lw = (size_t)C_ * C_ * 9;
    float* loss_ptr = out + (size_t)B_ * KTOP * 6;

    WtArgs wa;
    wa.src[0] = cls_w;        wa.cout[0] = 128;
    wa.src[1] = bbox_w;       wa.cout[1] = 128;
    wa.src[2] = off_w;        wa.cout[2] = 128;
    wa.src[3] = cls_w + lw;   wa.cout[3] = 128;
    wa.src[4] = bbox_w + lw;  wa.cout[4] = 128;
    wa.src[5] = off_w + lw;   wa.cout[5] = 128;
    wa.src[6] = cls_score_w;  wa.cout[6] = NCLS_;

    const size_t FUSED_NEED = 6 * XSZ + 2 * P_BYTES + WT_BYTES + SM_BYTES;

    #define WIMG(i) (WT + (size_t)(i) * (WIMG_B / 2))

    if (ws_size >= FUSED_NEED) {
        // ------------------- fused 3-tower path -------------------
        // slots 0..5 of size XSZ: XA0 XA1 XA2 XB Bfb Bfo
        char* XA0 = ws;
        char* XA1 = ws + XSZ;
        char* XA2 = ws + 2 * XSZ;
        char* XB  = ws + 3 * XSZ;
        float* Bfb = (float*)(ws + 4 * XSZ);
        float* Bfo = (float*)(ws + 5 * XSZ);
        float* L   = (float*)XA0;          // overlays XA0 (dead after stage 2)
        unsigned* keys = (unsigned*)XA1;   // overlays XA1 (dead after stage 2)
        float* WH  = (float*)(ws + 6 * XSZ);
        float* OFF = (float*)(ws + 6 * XSZ + P_BYTES);
        unsigned short* WT = (unsigned short*)(ws + 6 * XSZ + 2 * P_BYTES);
        unsigned* sm = (unsigned*)(ws + 6 * XSZ + 2 * P_BYTES + WT_BYTES);

        unsigned* hist1 = sm;
        unsigned* hist2 = sm + 4 * 2048;
        unsigned* hist3 = sm + 8 * 2048;
        unsigned* bin1  = sm + 8 * 2048 + 4 * 1024;
        unsigned* gt1   = bin1 + 4;
        unsigned* pfx2  = bin1 + 8;
        unsigned* gt2   = bin1 + 12;
        unsigned* Tk    = bin1 + 16;
        unsigned* gt3   = bin1 + 20;
        unsigned* cntA  = bin1 + 24;
        unsigned* cntB  = bin1 + 28;
        uint2*    listA = (uint2*)(bin1 + 32);
        unsigned* listB = (unsigned*)(bin1 + 32 + 2 * B_ * KTOP);

        // borders for 4 X'' buffers (slots 0..3)
        init_k<<<210, 256, 0, stream>>>(XA0, 4, sm, loss_ptr);
        wtx_k<<<dim3(72, 1, NIMG), 256, 0, stream>>>(wa, WT);

        // stage 1: three L1 convs fused (feature -> XA0/XA1/XA2)
        F3Args f3;
        f3.wt[0] = WIMG(0); f3.bias[0] = cls_b;  f3.outx[0] = XA0;
        f3.wt[1] = WIMG(1); f3.bias[1] = bbox_b; f3.outx[1] = XA1;
        f3.wt[2] = WIMG(2); f3.bias[2] = off_b;  f3.outx[2] = XA2;
        convF3_k<<<dim3(512, 3), 256, 0, stream>>>(feature, f3);

        // stage 2: three L2 convs fused (XA* -> XB / Bfb / Bfo)
        X3Args x3;
        x3.xin[0] = XA0; x3.wt[0] = WIMG(3); x3.bias[0] = cls_b + C_;
        x3.outf[0] = nullptr; x3.outx[0] = XB; x3.xout[0] = 1;
        x3.xin[1] = XA1; x3.wt[1] = WIMG(4); x3.bias[1] = bbox_b + C_;
        x3.outf[1] = Bfb; x3.outx[1] = nullptr; x3.xout[1] = 0;
        x3.xin[2] = XA2; x3.wt[2] = WIMG(5); x3.bias[2] = off_b + C_;
        x3.outf[2] = Bfo; x3.outx[2] = nullptr; x3.xout[2] = 0;
        convX3_k<<<dim3(512, 3), 256, 0, stream>>>(x3);

        // stage 3: score conv (XB -> L, overlays XA0) + fused 2-head convs
        conv_x_k<0, 0><<<512, 256, 0, stream>>>(XB, WIMG(6), cls_score_b, L, nullptr, NCLS_);
        conv2out2_k<<<dim3(64, 4, 2), 256, 0, stream>>>(
            Bfb, Bfo, bbox_pred_w, center_off_w, bbox_pred_b, center_off_b, WH, OFF);

        lnh_k<<<dim3(512, B_), 256, 0, stream>>>(L, targets, loss_ptr, keys, hist1);

        dim3 hgrid(512, B_);
        scan_k<2048, 1><<<B_, 256, 0, stream>>>(hist1, nullptr, nullptr, bin1, gt1);
        hist2_k<<<hgrid, 256, 0, stream>>>(keys, bin1, hist2);
        scan_k<2048, 2><<<B_, 256, 0, stream>>>(hist2, bin1, gt1, pfx2, gt2);
        hist3_k<<<hgrid, 256, 0, stream>>>(keys, pfx2, hist3);
        scan_k<1024, 3><<<B_, 256, 0, stream>>>(hist3, pfx2, gt2, Tk, gt3);
        select_k<<<hgrid, 256, 0, stream>>>(keys, Tk, cntA, cntB, listA, listB);

        finalize_k<<<B_, 128, 0, stream>>>(cntA, cntB, listA, listB, Tk, WH, OFF, out);
    } else {
        // ------------------- fallback: R7 champion sequence -------------------
        char* XA = ws;
        char* XB = ws + XSZ;
        float* L   = (float*)(ws + 2 * XSZ);
        float* WH  = (float*)(ws + 2 * XSZ + L_BYTES);
        float* OFF = (float*)(ws + 2 * XSZ + L_BYTES + P_BYTES);
        unsigned short* WT = (unsigned short*)(ws + 2 * XSZ + L_BYTES + 2 * P_BYTES);
        unsigned* sm = (unsigned*)(ws + 2 * XSZ + L_BYTES + 2 * P_BYTES + WT_BYTES);
        float* Bf = (float*)XB;
        unsigned* keys = (unsigned*)XB;

        unsigned* hist1 = sm;
        unsigned* hist2 = sm + 4 * 2048;
        unsigned* hist3 = sm + 8 * 2048;
        unsigned* bin1  = sm + 8 * 2048 + 4 * 1024;
        unsigned* gt1   = bin1 + 4;
        unsigned* pfx2  = bin1 + 8;
        unsigned* gt2   = bin1 + 12;
        unsigned* Tk    = bin1 + 16;
        unsigned* gt3   = bin1 + 20;
        unsigned* cntA  = bin1 + 24;
        unsigned* cntB  = bin1 + 28;
        uint2*    listA = (uint2*)(bin1 + 32);
        unsigned* listB = (unsigned*)(bin1 + 32 + 2 * B_ * KTOP);

        init_k<<<145, 256, 0, stream>>>(XA, 2, sm, loss_ptr);
        wtx_k<<<dim3(72, 1, NIMG), 256, 0, stream>>>(wa, WT);

        // cls tower -> logits L
        conv_f_k<1, 1><<<512, 256, 0, stream>>>(feature, WIMG(0), cls_b,       nullptr, XA, 128);
        conv_x_k<1, 1><<<512, 256, 0, stream>>>(XA,      WIMG(3), cls_b + C_,  nullptr, XB, 128);
        conv_x_k<0, 0><<<512, 256, 0, stream>>>(XB,      WIMG(6), cls_score_b, L, nullptr, NCLS_);
        // bbox tower -> WH
        conv_f_k<1, 1><<<512, 256, 0, stream>>>(feature, WIMG(1), bbox_b,      nullptr, XA, 128);
        conv_x_k<1, 0><<<512, 256, 0, stream>>>(XA,      WIMG(4), bbox_b + C_, Bf, nullptr, 128);
        conv2out_k<<<dim3(64, 4), 256, 0, stream>>>(Bf, bbox_pred_w, bbox_pred_b, WH);
        // off tower -> OFF
        conv_f_k<1, 1><<<512, 256, 0, stream>>>(feature, WIMG(2), off_b,       nullptr, XA, 128);
        conv_x_k<1, 0><<<512, 256, 0, stream>>>(XA,      WIMG(5), off_b + C_,  Bf, nullptr, 128);
        conv2out_k<<<dim3(64, 4), 256, 0, stream>>>(Bf, center_off_w, center_off_b, OFF);

        lnh_k<<<dim3(512, B_), 256, 0, stream>>>(L, targets, loss_ptr, keys, hist1);

        dim3 hgrid(512, B_);
        scan_k<2048, 1><<<B_, 256, 0, stream>>>(hist1, nullptr, nullptr, bin1, gt1);
        hist2_k<<<hgrid, 256, 0, stream>>>(keys, bin1, hist2);
        scan_k<2048, 2><<<B_, 256, 0, stream>>>(hist2, bin1, gt1, pfx2, gt2);
        hist3_k<<<hgrid, 256, 0, stream>>>(keys, pfx2, hist3);
        scan_k<1024, 3><<<B_, 256, 0, stream>>>(hist3, pfx2, gt2, Tk, gt3);
        select_k<<<hgrid, 256, 0, stream>>>(keys, Tk, cntA, cntB, listA, listB);

        finalize_k<<<B_, 128, 0, stream>>>(cntA, cntB, listA, listB, Tk, WH, OFF, out);
    }
}